// Round 11
// baseline (3298.068 us; speedup 1.0000x reference)
//
#include <hip/hip_runtime.h>
#include <cstdint>

// Problem constants
#define E_ 8
#define D_ 1024
#define H_ 4096
#define NTOK 16384   // B*S = 4*4096

typedef unsigned short ushort_t;
typedef __attribute__((ext_vector_type(8))) short short8;
typedef __attribute__((ext_vector_type(4))) float f32x4;

__device__ __forceinline__ ushort_t f2bf(float f) {
  uint32_t u = __builtin_bit_cast(uint32_t, f);
  uint32_t r = (u + 0x7fffu + ((u >> 16) & 1u)) >> 16;  // RNE
  return (ushort_t)r;
}

__device__ __forceinline__ void gload_lds16(const void* g, void* l) {
  __builtin_amdgcn_global_load_lds(
      (const __attribute__((address_space(1))) uint32_t*)g,
      (__attribute__((address_space(3))) uint32_t*)l, 16, 0, 0);
}

// ---------------- init: zero cursor + rawbase ----------------
__global__ void init_kernel(int* cursor, float* rawbase) {
  int tid = threadIdx.x + blockIdx.x * 256;
  if (tid < 8) cursor[tid] = 0;
  if (tid < E_ * D_) rawbase[tid] = 0.f;   // grid 32*256 = 8192 threads
}

// ---------------- transpose fp32 [E][R][C] -> bf16 [E][C][R], 64x64 tiles ----------------
// float4 (16B/lane) reads; bf16 transposed in LDS; short8 (16B) coalesced writes.
// FUSE=1 (W2 path): also accumulate rawbase[e][d] += sum_h relu(b1[e][h]) * W2[e][h][d]
template <int FUSE>
__global__ void transpose_bf16(const float* __restrict__ in, ushort_t* __restrict__ out,
                               int R, int C, const float* __restrict__ b1,
                               float* __restrict__ rawbase) {
  __shared__ ushort_t t[64][70];   // [c][r]
  __shared__ float scs[16][64];
  __shared__ float relu_b1[64];
  const int e = blockIdx.z;
  const float* ip = in + (size_t)e * R * C;
  ushort_t* op = out + (size_t)e * R * C;
  const int c0 = blockIdx.x * 64, r0 = blockIdx.y * 64;
  const int tid = threadIdx.x;
  if (FUSE) {
    if (tid < 64) relu_b1[tid] = fmaxf(b1[e * R + r0 + tid], 0.f);
    __syncthreads();
  }
  const int rsub = tid >> 4;        // 0..15
  const int c4 = (tid & 15) * 4;    // 0,4..60
  float s0 = 0.f, s1 = 0.f, s2 = 0.f, s3 = 0.f;
#pragma unroll
  for (int q = 0; q < 4; ++q) {
    int r = q * 16 + rsub;
    float4 v = *(const float4*)&ip[(size_t)(r0 + r) * C + c0 + c4];
    t[c4 + 0][r] = f2bf(v.x);
    t[c4 + 1][r] = f2bf(v.y);
    t[c4 + 2][r] = f2bf(v.z);
    t[c4 + 3][r] = f2bf(v.w);
    if (FUSE) {
      float rb = relu_b1[r];
      s0 += rb * v.x; s1 += rb * v.y; s2 += rb * v.z; s3 += rb * v.w;
    }
  }
  if (FUSE) {
    scs[rsub][c4 + 0] = s0; scs[rsub][c4 + 1] = s1;
    scs[rsub][c4 + 2] = s2; scs[rsub][c4 + 3] = s3;
  }
  __syncthreads();
  if (FUSE && tid < 64) {
    float tot = 0.f;
#pragma unroll
    for (int g = 0; g < 16; ++g) tot += scs[g][tid];
    atomicAdd(&rawbase[e * D_ + c0 + tid], tot);
  }
#pragma unroll
  for (int it = 0; it < 2; ++it) {
    int idx = it * 256 + tid;        // 0..511
    int c = idx >> 3, g = idx & 7;   // c 0..63, 8 B-groups of 8 rows
    short8 v;
#pragma unroll
    for (int k = 0; k < 8; ++k) v[k] = (short)t[c][g * 8 + k];
    *(short8*)&op[(size_t)(c0 + c) * R + r0 + g * 8] = v;
  }
}

// adj[e][d] = sum_i (rawbase[i][d] + b2[i][d]) - rawbase[e][d]
__global__ void adj_kernel(const float* __restrict__ rawbase, const float* __restrict__ b2,
                           float* __restrict__ adj) {
  int i = blockIdx.x * 256 + threadIdx.x;  // 8192
  int d = i & (D_ - 1);
  int e = i >> 10;
  float tot = 0.f;
#pragma unroll
  for (int ii = 0; ii < E_; ++ii) tot += rawbase[ii * D_ + d] + b2[ii * D_ + d];
  adj[i] = tot - rawbase[e * D_ + d];
}

// ---------------- router: fp32 logits -> argmax (first-max tiebreak). NO atomics ----------------
__global__ void router_kernel(const float* __restrict__ x, const float* __restrict__ Wr,
                              const float* __restrict__ br, int* __restrict__ idx) {
  __shared__ float wr_s[E_][D_];   // transposed Wr: wr_s[e][d]
  const int tid = threadIdx.x;
  for (int j = tid; j < E_ * D_; j += 256) {
    int e = j & 7, d = j >> 3;
    wr_s[e][d] = Wr[j];
  }
  __syncthreads();
  const int wid = tid >> 6, l = tid & 63;
  const int t0 = blockIdx.x * 32 + wid * 8;
  for (int tt = 0; tt < 8; ++tt) {
    int t = t0 + tt;
    const float4* xr4 = (const float4*)(x + (size_t)t * D_);
    float s[E_];
#pragma unroll
    for (int e = 0; e < E_; ++e) s[e] = 0.f;
#pragma unroll
    for (int q = 0; q < 4; ++q) {
      float4 xv = xr4[q * 64 + l];
#pragma unroll
      for (int e = 0; e < E_; ++e) {
        const float4 wv = *(const float4*)&wr_s[e][(q * 64 + l) * 4];
        s[e] += xv.x * wv.x + xv.y * wv.y + xv.z * wv.z + xv.w * wv.w;
      }
    }
#pragma unroll
    for (int e = 0; e < E_; ++e) {
#pragma unroll
      for (int off = 32; off > 0; off >>= 1) s[e] += __shfl_xor(s[e], off, 64);
    }
    if (l == 0) {
      float best = s[0] + br[0];
      int bi = 0;
#pragma unroll
      for (int e = 1; e < E_; ++e) {
        float v = s[e] + br[e];
        if (v > best) { best = v; bi = e; }   // strict >: first-max like argmax
      }
      idx[t] = bi;
    }
  }
}

// ---------------- fused count + scan + worklist build (single block, no atomics) ----------------
// 256x256 tiles. work1 item = (e<<16)|(tm<<8)|tn (16 tn); work2 same (4 tn). meta:[0]=n1 [1]=n2
__global__ void count_scan_build(const int* __restrict__ idx, int* __restrict__ offsets,
                                 int* __restrict__ work1, int* __restrict__ work2,
                                 int* __restrict__ meta) {
  __shared__ int hist[256][E_];
  __shared__ int nt[E_], b1s[E_], b2s[E_];
  const int tid = threadIdx.x;
  int c[E_];
#pragma unroll
  for (int e = 0; e < E_; ++e) c[e] = 0;
  for (int t = tid; t < NTOK; t += 256) ++c[idx[t]];
#pragma unroll
  for (int e = 0; e < E_; ++e) hist[tid][e] = c[e];
  __syncthreads();
  if (tid == 0) {
    int acc = 0, w1 = 0, w2 = 0;
    for (int e = 0; e < E_; ++e) {
      int s = 0;
      for (int i = 0; i < 256; ++i) s += hist[i][e];
      offsets[e] = acc;
      acc += s;
      int n = (s + 255) >> 8;
      nt[e] = n;
      b1s[e] = w1; w1 += n * (H_ / 256);
      b2s[e] = w2; w2 += n * (D_ / 256);
    }
    offsets[E_] = acc;
    meta[0] = w1;
    meta[1] = w2;
  }
  __syncthreads();
  if (tid < E_) {
    const int e = tid, n = nt[e];
    int p = b1s[e];
    for (int tn = 0; tn < H_ / 256; ++tn)
      for (int tm = 0; tm < n; ++tm)
        work1[p++] = (e << 16) | (tm << 8) | tn;
  } else if (tid < 2 * E_) {
    const int e = tid - E_, n = nt[e];
    int p = b2s[e];
    for (int tn = 0; tn < D_ / 256; ++tn)
      for (int tm = 0; tm < n; ++tm)
        work2[p++] = (e << 16) | (tm << 8) | tn;
  }
}

// ---------------- scatter: 64 tokens/block; warp-ballot slot assignment (8 atomics/block) ----------------
__global__ void scatter_kernel(const float* __restrict__ x, const int* __restrict__ idx,
                               const int* __restrict__ offsets, int* __restrict__ cursor,
                               int* __restrict__ perm, ushort_t* __restrict__ xg) {
  __shared__ int slots[64];
  const int tid = threadIdx.x;
  const int t0 = blockIdx.x * 64;
  if (tid < 64) {
    const int t = t0 + tid;
    const int e = idx[t];
    const unsigned long long lanebit = 1ull << tid;
    int slot = 0;
#pragma unroll
    for (int ee = 0; ee < E_; ++ee) {
      unsigned long long m = __ballot(e == ee);
      if (e == ee) {
        int lead = __ffsll((long long)m) - 1;
        int base = 0;
        if (tid == lead) base = atomicAdd(&cursor[ee], __popcll(m));
        base = __shfl(base, lead, 64);
        slot = offsets[ee] + base + __popcll(m & (lanebit - 1));
      }
    }
    slots[tid] = slot;
    perm[slot] = t;
  }
  __syncthreads();
  // gather+convert: whole block copies each of the 64 rows (256 thr x 1 float4 = 1024 f32)
  for (int r = 0; r < 64; ++r) {
    const int t = t0 + r;
    const int slot = slots[r];
    float4 v = *(const float4*)(x + (size_t)t * D_ + tid * 4);
    ushort4 o;
    o.x = f2bf(v.x); o.y = f2bf(v.y); o.z = f2bf(v.z); o.w = f2bf(v.w);
    *(ushort4*)(xg + (size_t)slot * D_ + tid * 4) = o;
  }
}

// ---------------- grouped GEMM: 256x256 tile, BK=32, 2-buffer, 2 blocks/CU ----------------
// R6's tile/swizzle/fragment structure, but LDS shrunk to 2 bufs x {A,B} x 16 KiB = 64 KiB
// -> 2 resident blocks/CU (16 waves/CU, 4 waves/SIMD). The per-step vmcnt(0)+barrier drain
// of one block overlaps the other block's compute (m114 cross-wave overlap; m97's best
// configs were all multi-block). 512 threads = 8 waves (2 M x 4 N), per-wave 128x64.
// Two logical 64B rows pack into one 128B phys row; XOR swizzle keeps ds_read_b128 aliasing
// at 2-way (free). Per step: STAGE(kt+1 into buf^1) -> 12 ds_read_b128 + 32 MFMA on buf
// -> s_waitcnt vmcnt(0) -> s_barrier.
// MODE 1: hb = relu(xg@W1t^T+b1) bf16 ; MODE 2: out[perm] = hb@W2t^T+adj (plain f32 stores).

template <int MODE>
__global__ __launch_bounds__(512, 4) void ffn_gemm(
    const ushort_t* __restrict__ A_all, const ushort_t* __restrict__ Bw,
    const float* __restrict__ bias, const int* __restrict__ offs,
    const int* __restrict__ perm, float* __restrict__ out, ushort_t* __restrict__ hbo,
    const int* __restrict__ work, const int* __restrict__ nw_p) {
  constexpr int KdF = (MODE == 1) ? D_ : H_;    // K (= row stride of A and B^T)
  constexpr int Nd = (MODE == 1) ? H_ : D_;
  constexpr int NKT = KdF / 32;                 // 32 / 128 K-steps

  const int n1 = *nw_p;
  int bid = blockIdx.x;
  if (bid >= n1) return;
  {  // m204 bijective XCD swizzle over the worklist
    int q = n1 >> 3, r = n1 & 7;
    int xcd = bid & 7, pos = bid >> 3;
    bid = (xcd < r ? xcd * (q + 1) : r * (q + 1) + (xcd - r) * q) + pos;
  }
  const int item = work[bid];
  const int e = (item >> 16) & 255, tm = (item >> 8) & 255, tn = item & 255;
  const int ms = offs[e];
  const int M = offs[e + 1] - ms;

  __shared__ __align__(16) ushort_t lds[2][2][8192];  // 2 bufs x {A,B} x 16KB = 64 KiB

  const int tid = threadIdx.x;
  const int wid = tid >> 6, l = tid & 63;
  const int wm = wid >> 2, wn = wid & 3;
  const int lr = l & 15, lh = l >> 4;

  const ushort_t* Ab = A_all + (size_t)ms * KdF;
  const ushort_t* Bb = Bw + (size_t)e * ((size_t)Nd * KdF);
  const int arow0 = tm * 256;
  const int brow0 = tn * 256;
  const int rowmaxA = M - 1;

  // per-thread staging source offsets (elements). Slot s -> phys row P=s>>3, stored unit
  // U=s&7; logical unit Ur = U ^ (P&7); logical row r = 2P + (Ur>>2), col-unit u = Ur&3.
  int a_src[2], b_src[2];
#pragma unroll
  for (int c = 0; c < 2; ++c) {
    int s = c * 512 + tid;
    int P = s >> 3, U = s & 7;
    int Ur = U ^ (P & 7);
    int r = 2 * P + (Ur >> 2);
    int u = Ur & 3;
    int ga = arow0 + r;
    if (ga > rowmaxA) ga = rowmaxA;
    a_src[c] = ga * KdF + u * 8;
    b_src[c] = (brow0 + r) * KdF + u * 8;
  }

#define STAGE(buf, kt)                                                                   \
  _Pragma("unroll") for (int c_ = 0; c_ < 2; ++c_) {                                     \
    gload_lds16(Ab + a_src[c_] + (kt) * 32, &lds[buf][0][(c_ * 512 + wid * 64) * 8]);    \
    gload_lds16(Bb + b_src[c_] + (kt) * 32, &lds[buf][1][(c_ * 512 + wid * 64) * 8]);    \
  }

// logical (r, lh) -> ushort offset within a 16KB half
#define AOFF(r) (((((r) >> 1)) << 6) + ((((lh) + (((r) & 1) << 2)) ^ (((r) >> 1) & 7)) << 3))

  f32x4 acc[8][4];
#pragma unroll
  for (int i = 0; i < 8; ++i)
#pragma unroll
    for (int j = 0; j < 4; ++j) acc[i][j] = (f32x4){0.f, 0.f, 0.f, 0.f};

  // prologue: tile 0 into buf 0
  STAGE(0, 0)
  asm volatile("s_waitcnt vmcnt(0)" ::: "memory");
  __builtin_amdgcn_s_barrier();

#pragma unroll 4
  for (int kt = 0; kt < NKT; ++kt) {
    const int cur = kt & 1;
    if (kt + 1 < NKT) { STAGE(cur ^ 1, kt + 1) }
    const ushort_t* la = &lds[cur][0][0];
    const ushort_t* lb = &lds[cur][1][0];
    short8 af[8], bq[4];
#pragma unroll
    for (int i = 0; i < 8; ++i)
      af[i] = *(const short8*)&la[AOFF(wm * 128 + i * 16 + lr)];
#pragma unroll
    for (int j = 0; j < 4; ++j)
      bq[j] = *(const short8*)&lb[AOFF(wn * 64 + j * 16 + lr)];
#pragma unroll
    for (int i = 0; i < 8; ++i)
#pragma unroll
      for (int j = 0; j < 4; ++j)
        acc[i][j] = __builtin_amdgcn_mfma_f32_16x16x32_bf16(af[i], bq[j], acc[i][j], 0, 0, 0);
    asm volatile("s_waitcnt vmcnt(0)" ::: "memory");  // next buf fully staged (this wave)
    __builtin_amdgcn_s_barrier();                     // ... and for all waves
  }

  // epilogue: C[row = tm*256 + wm*128 + i*16 + lh*4 + rr][col = tn*256 + wn*64 + j*16 + lr]
  const int gcolbase = tn * 256 + wn * 64 + lr;
  float bv[4];
#pragma unroll
  for (int j = 0; j < 4; ++j) bv[j] = bias[e * Nd + gcolbase + j * 16];
#pragma unroll
  for (int i = 0; i < 8; ++i) {
#pragma unroll
    for (int rr = 0; rr < 4; ++rr) {
      int grow = tm * 256 + wm * 128 + i * 16 + lh * 4 + rr;
      if (grow < M) {
        if (MODE == 1) {
          size_t rowoff = (size_t)(ms + grow) * H_;
#pragma unroll
          for (int j = 0; j < 4; ++j) {
            float v = acc[i][j][rr] + bv[j];
            v = fmaxf(v, 0.f);
            hbo[rowoff + gcolbase + j * 16] = f2bf(v);
          }
        } else {
          int tok = perm[ms + grow];
          size_t rowoff = (size_t)tok * D_;
#pragma unroll
          for (int j = 0; j < 4; ++j)
            out[rowoff + gcolbase + j * 16] = acc[i][j][rr] + bv[j];
        }
      }
    }
  }
#undef STAGE
#undef AOFF
}

extern "C" void kernel_launch(void* const* d_in, const int* in_sizes, int n_in,
                              void* d_out, int out_size, void* d_ws, size_t ws_size,
                              hipStream_t stream) {
  const float* x  = (const float*)d_in[0];
  const float* W1 = (const float*)d_in[1];
  const float* b1 = (const float*)d_in[2];
  const float* W2 = (const float*)d_in[3];
  const float* b2 = (const float*)d_in[4];
  const float* Wr = (const float*)d_in[5];
  const float* br = (const float*)d_in[6];
  float* out = (float*)d_out;

  // workspace layout (needs ~302.3 MB)
  char* ws = (char*)d_ws;
  ushort_t* W1t   = (ushort_t*)(ws);                    // [E][H][D] bf16: 67108864 B
  ushort_t* W2t   = (ushort_t*)(ws + 67108864);         // [E][D][H] bf16: 67108864 B
  ushort_t* xg    = (ushort_t*)(ws + 134217728);        // [N][D]   bf16: 33554432 B
  ushort_t* hb    = (ushort_t*)(ws + 167772160);        // [N][H]   bf16: 134217728 B
  float*    rawbase = (float*)(ws + 301989888);         // [E][D] f32
  float*    adj   = (float*)(ws + 302022656);           // [E][D] f32
  int*      idx   = (int*)(ws + 302055424);             // [N]
  int*      perm  = (int*)(ws + 302120960);             // [N]
  int*      cursor = (int*)(ws + 302186496);            // 8
  int*      offsets = (int*)(ws + 302186624);           // 9 ints
  int*      meta   = (int*)(ws + 302186752);            // [n1, n2]
  int*      work1  = (int*)(ws + 302186880);            // <=2048 ints
  int*      work2  = (int*)(ws + 302195072);            // <=2048 ints

  init_kernel<<<32, 256, 0, stream>>>(cursor, rawbase);
  transpose_bf16<0><<<dim3(H_ / 64, D_ / 64, E_), 256, 0, stream>>>(W1, W1t, D_, H_,
                                                                    nullptr, nullptr);
  transpose_bf16<1><<<dim3(D_ / 64, H_ / 64, E_), 256, 0, stream>>>(W2, W2t, H_, D_,
                                                                    b1, rawbase);
  adj_kernel<<<32, 256, 0, stream>>>(rawbase, b2, adj);
  router_kernel<<<512, 256, 0, stream>>>(x, Wr, br, idx);
  count_scan_build<<<1, 256, 0, stream>>>(idx, offsets, work1, work2, meta);
  scatter_kernel<<<NTOK / 64, 256, 0, stream>>>(x, idx, offsets, cursor, perm, xg);
  // worst-case tile counts: sum_e ceil(cnt_e/256) <= 71 -> n1 <= 71*16=1136, n2 <= 71*4=284
  ffn_gemm<1><<<1136, 512, 0, stream>>>(xg, W1t, b1, offsets, nullptr, nullptr, hb,
                                        work1, meta + 0);
  ffn_gemm<2><<<284, 512, 0, stream>>>(hb, W2t, adj, offsets, perm, out, nullptr,
                                       work2, meta + 1);
}

// Round 12
// 621.301 us; speedup vs baseline: 5.3083x; 5.3083x over previous
//
#include <hip/hip_runtime.h>
#include <cstdint>

// Problem constants
#define E_ 8
#define D_ 1024
#define H_ 4096
#define NTOK 16384   // B*S = 4*4096

typedef unsigned short ushort_t;
typedef __attribute__((ext_vector_type(8))) short short8;
typedef __attribute__((ext_vector_type(4))) float f32x4;

__device__ __forceinline__ ushort_t f2bf(float f) {
  uint32_t u = __builtin_bit_cast(uint32_t, f);
  uint32_t r = (u + 0x7fffu + ((u >> 16) & 1u)) >> 16;  // RNE
  return (ushort_t)r;
}

__device__ __forceinline__ void gload_lds16(const void* g, void* l) {
  __builtin_amdgcn_global_load_lds(
      (const __attribute__((address_space(1))) uint32_t*)g,
      (__attribute__((address_space(3))) uint32_t*)l, 16, 0, 0);
}

// ---------------- init: zero cursor + rawbase ----------------
__global__ void init_kernel(int* cursor, float* rawbase) {
  int tid = threadIdx.x + blockIdx.x * 256;
  if (tid < 8) cursor[tid] = 0;
  if (tid < E_ * D_) rawbase[tid] = 0.f;   // grid 32*256 = 8192 threads
}

// ---------------- transpose fp32 [E][R][C] -> bf16 [E][C][R], 64x64 tiles ----------------
// float4 (16B/lane) reads; bf16 transposed in LDS; short8 (16B) coalesced writes.
// FUSE=1 (W2 path): also accumulate rawbase[e][d] += sum_h relu(b1[e][h]) * W2[e][h][d]
template <int FUSE>
__global__ void transpose_bf16(const float* __restrict__ in, ushort_t* __restrict__ out,
                               int R, int C, const float* __restrict__ b1,
                               float* __restrict__ rawbase) {
  __shared__ ushort_t t[64][70];   // [c][r]
  __shared__ float scs[16][64];
  __shared__ float relu_b1[64];
  const int e = blockIdx.z;
  const float* ip = in + (size_t)e * R * C;
  ushort_t* op = out + (size_t)e * R * C;
  const int c0 = blockIdx.x * 64, r0 = blockIdx.y * 64;
  const int tid = threadIdx.x;
  if (FUSE) {
    if (tid < 64) relu_b1[tid] = fmaxf(b1[e * R + r0 + tid], 0.f);
    __syncthreads();
  }
  const int rsub = tid >> 4;        // 0..15
  const int c4 = (tid & 15) * 4;    // 0,4..60
  float s0 = 0.f, s1 = 0.f, s2 = 0.f, s3 = 0.f;
#pragma unroll
  for (int q = 0; q < 4; ++q) {
    int r = q * 16 + rsub;
    float4 v = *(const float4*)&ip[(size_t)(r0 + r) * C + c0 + c4];
    t[c4 + 0][r] = f2bf(v.x);
    t[c4 + 1][r] = f2bf(v.y);
    t[c4 + 2][r] = f2bf(v.z);
    t[c4 + 3][r] = f2bf(v.w);
    if (FUSE) {
      float rb = relu_b1[r];
      s0 += rb * v.x; s1 += rb * v.y; s2 += rb * v.z; s3 += rb * v.w;
    }
  }
  if (FUSE) {
    scs[rsub][c4 + 0] = s0; scs[rsub][c4 + 1] = s1;
    scs[rsub][c4 + 2] = s2; scs[rsub][c4 + 3] = s3;
  }
  __syncthreads();
  if (FUSE && tid < 64) {
    float tot = 0.f;
#pragma unroll
    for (int g = 0; g < 16; ++g) tot += scs[g][tid];
    atomicAdd(&rawbase[e * D_ + c0 + tid], tot);
  }
#pragma unroll
  for (int it = 0; it < 2; ++it) {
    int idx = it * 256 + tid;        // 0..511
    int c = idx >> 3, g = idx & 7;   // c 0..63, 8 B-groups of 8 rows
    short8 v;
#pragma unroll
    for (int k = 0; k < 8; ++k) v[k] = (short)t[c][g * 8 + k];
    *(short8*)&op[(size_t)(c0 + c) * R + r0 + g * 8] = v;
  }
}

// adj[e][d] = sum_i (rawbase[i][d] + b2[i][d]) - rawbase[e][d]
__global__ void adj_kernel(const float* __restrict__ rawbase, const float* __restrict__ b2,
                           float* __restrict__ adj) {
  int i = blockIdx.x * 256 + threadIdx.x;  // 8192
  int d = i & (D_ - 1);
  int e = i >> 10;
  float tot = 0.f;
#pragma unroll
  for (int ii = 0; ii < E_; ++ii) tot += rawbase[ii * D_ + d] + b2[ii * D_ + d];
  adj[i] = tot - rawbase[e * D_ + d];
}

// ---------------- router: fp32 logits -> argmax (first-max tiebreak). NO atomics ----------------
__global__ void router_kernel(const float* __restrict__ x, const float* __restrict__ Wr,
                              const float* __restrict__ br, int* __restrict__ idx) {
  __shared__ float wr_s[E_][D_];   // transposed Wr: wr_s[e][d]
  const int tid = threadIdx.x;
  for (int j = tid; j < E_ * D_; j += 256) {
    int e = j & 7, d = j >> 3;
    wr_s[e][d] = Wr[j];
  }
  __syncthreads();
  const int wid = tid >> 6, l = tid & 63;
  const int t0 = blockIdx.x * 32 + wid * 8;
  for (int tt = 0; tt < 8; ++tt) {
    int t = t0 + tt;
    const float4* xr4 = (const float4*)(x + (size_t)t * D_);
    float s[E_];
#pragma unroll
    for (int e = 0; e < E_; ++e) s[e] = 0.f;
#pragma unroll
    for (int q = 0; q < 4; ++q) {
      float4 xv = xr4[q * 64 + l];
#pragma unroll
      for (int e = 0; e < E_; ++e) {
        const float4 wv = *(const float4*)&wr_s[e][(q * 64 + l) * 4];
        s[e] += xv.x * wv.x + xv.y * wv.y + xv.z * wv.z + xv.w * wv.w;
      }
    }
#pragma unroll
    for (int e = 0; e < E_; ++e) {
#pragma unroll
      for (int off = 32; off > 0; off >>= 1) s[e] += __shfl_xor(s[e], off, 64);
    }
    if (l == 0) {
      float best = s[0] + br[0];
      int bi = 0;
#pragma unroll
      for (int e = 1; e < E_; ++e) {
        float v = s[e] + br[e];
        if (v > best) { best = v; bi = e; }   // strict >: first-max like argmax
      }
      idx[t] = bi;
    }
  }
}

// ---------------- fused count + scan + worklist build (single block, no atomics) ----------------
// 256x256 tiles. work1 item = (e<<16)|(tm<<8)|tn (16 tn); work2 same (4 tn). meta:[0]=n1 [1]=n2
// Histogram reduced in parallel: half-warp h (32 lanes) shuffle-reduces expert h.
__global__ void count_scan_build(const int* __restrict__ idx, int* __restrict__ offsets,
                                 int* __restrict__ work1, int* __restrict__ work2,
                                 int* __restrict__ meta) {
  __shared__ int hist[256][E_];
  __shared__ int esum[E_];
  __shared__ int nt[E_], b1s[E_], b2s[E_];
  const int tid = threadIdx.x;
  int c[E_];
#pragma unroll
  for (int e = 0; e < E_; ++e) c[e] = 0;
  for (int t = tid; t < NTOK; t += 256) ++c[idx[t]];
#pragma unroll
  for (int e = 0; e < E_; ++e) hist[tid][e] = c[e];
  __syncthreads();
  {  // parallel expert sums: 8 half-warps, one expert each
    const int hw = tid >> 5, l32 = tid & 31;
    int s = 0;
#pragma unroll
    for (int i = 0; i < 8; ++i) s += hist[i * 32 + l32][hw];
#pragma unroll
    for (int off = 16; off > 0; off >>= 1) s += __shfl_xor(s, off, 64);
    if (l32 == 0) esum[hw] = s;
  }
  __syncthreads();
  if (tid == 0) {
    int acc = 0, w1 = 0, w2 = 0;
    for (int e = 0; e < E_; ++e) {
      int s = esum[e];
      offsets[e] = acc;
      acc += s;
      int n = (s + 255) >> 8;
      nt[e] = n;
      b1s[e] = w1; w1 += n * (H_ / 256);
      b2s[e] = w2; w2 += n * (D_ / 256);
    }
    offsets[E_] = acc;
    meta[0] = w1;
    meta[1] = w2;
  }
  __syncthreads();
  if (tid < E_) {
    const int e = tid, n = nt[e];
    int p = b1s[e];
    for (int tn = 0; tn < H_ / 256; ++tn)
      for (int tm = 0; tm < n; ++tm)
        work1[p++] = (e << 16) | (tm << 8) | tn;
  } else if (tid < 2 * E_) {
    const int e = tid - E_, n = nt[e];
    int p = b2s[e];
    for (int tn = 0; tn < D_ / 256; ++tn)
      for (int tm = 0; tm < n; ++tm)
        work2[p++] = (e << 16) | (tm << 8) | tn;
  }
}

// ---------------- scatter: 64 tokens/block; warp-ballot slot assignment (8 atomics/block) ----------------
__global__ void scatter_kernel(const float* __restrict__ x, const int* __restrict__ idx,
                               const int* __restrict__ offsets, int* __restrict__ cursor,
                               int* __restrict__ perm, ushort_t* __restrict__ xg) {
  __shared__ int slots[64];
  const int tid = threadIdx.x;
  const int t0 = blockIdx.x * 64;
  if (tid < 64) {
    const int t = t0 + tid;
    const int e = idx[t];
    const unsigned long long lanebit = 1ull << tid;
    int slot = 0;
#pragma unroll
    for (int ee = 0; ee < E_; ++ee) {
      unsigned long long m = __ballot(e == ee);
      if (e == ee) {
        int lead = __ffsll((long long)m) - 1;
        int base = 0;
        if (tid == lead) base = atomicAdd(&cursor[ee], __popcll(m));
        base = __shfl(base, lead, 64);
        slot = offsets[ee] + base + __popcll(m & (lanebit - 1));
      }
    }
    slots[tid] = slot;
    perm[slot] = t;
  }
  __syncthreads();
  // gather+convert: whole block copies each of the 64 rows (256 thr x 1 float4 = 1024 f32)
  for (int r = 0; r < 64; ++r) {
    const int t = t0 + r;
    const int slot = slots[r];
    float4 v = *(const float4*)(x + (size_t)t * D_ + tid * 4);
    ushort4 o;
    o.x = f2bf(v.x); o.y = f2bf(v.y); o.z = f2bf(v.z); o.w = f2bf(v.w);
    *(ushort4*)(xg + (size_t)slot * D_ + tid * 4) = o;
  }
}

// ---------------- grouped GEMM: 256x256 tile, BK=32, 4-buffer stage-ahead-3 pipeline ----------------
// (R6/R10 structure — best measured: 221 us, MfmaUtil 27.6%, 0 bank conflicts; + T5 setprio.)
// 512 threads = 8 waves (2 M x 4 N), per-wave output 128x64. LDS: 4 bufs x {A,B} of 16 KiB.
// Two logical 64B rows pack into one 128B phys row; XOR swizzle keeps ds_read_b128 aliasing
// at 2-way (free). Per step: STAGE(kt+3 clamped) -> 12 ds_read_b128 + 32 MFMA on buf[kt&3]
// -> s_waitcnt vmcnt(8) -> s_barrier.  MODE 1: hb = relu(xg@W1t^T+b1) bf16.
// MODE 2: out[perm] = hb@W2t^T + adj (plain f32 stores).
// NOTE (R11 lesson): acc[8][4]=128 AGPR + ~108 arch VGPR => 2 waves/SIMD max; do NOT
// request more via __launch_bounds__ or the accumulator spills to scratch (5 GB traffic).

template <int MODE>
__global__ __launch_bounds__(512, 2) void ffn_gemm(
    const ushort_t* __restrict__ A_all, const ushort_t* __restrict__ Bw,
    const float* __restrict__ bias, const int* __restrict__ offs,
    const int* __restrict__ perm, float* __restrict__ out, ushort_t* __restrict__ hbo,
    const int* __restrict__ work, const int* __restrict__ nw_p) {
  constexpr int KdF = (MODE == 1) ? D_ : H_;    // K (= row stride of A and B^T)
  constexpr int Nd = (MODE == 1) ? H_ : D_;
  constexpr int NKT = KdF / 32;                 // 32 / 128 K-steps

  const int n1 = *nw_p;
  int bid = blockIdx.x;
  if (bid >= n1) return;
  {  // m204 bijective XCD swizzle over the worklist
    int q = n1 >> 3, r = n1 & 7;
    int xcd = bid & 7, pos = bid >> 3;
    bid = (xcd < r ? xcd * (q + 1) : r * (q + 1) + (xcd - r) * q) + pos;
  }
  const int item = work[bid];
  const int e = (item >> 16) & 255, tm = (item >> 8) & 255, tn = item & 255;
  const int ms = offs[e];
  const int M = offs[e + 1] - ms;

  __shared__ __align__(16) ushort_t lds[4][2][8192];  // 4 bufs x {A,B} x 16KB = 128 KiB

  const int tid = threadIdx.x;
  const int wid = tid >> 6, l = tid & 63;
  const int wm = wid >> 2, wn = wid & 3;
  const int lr = l & 15, lh = l >> 4;

  const ushort_t* Ab = A_all + (size_t)ms * KdF;
  const ushort_t* Bb = Bw + (size_t)e * ((size_t)Nd * KdF);
  const int arow0 = tm * 256;
  const int brow0 = tn * 256;
  const int rowmaxA = M - 1;

  // per-thread staging source offsets (elements). Slot s -> phys row P=s>>3, stored unit
  // U=s&7; logical unit Ur = U ^ (P&7); logical row r = 2P + (Ur>>2), col-unit u = Ur&3.
  int a_src[2], b_src[2];
#pragma unroll
  for (int c = 0; c < 2; ++c) {
    int s = c * 512 + tid;
    int P = s >> 3, U = s & 7;
    int Ur = U ^ (P & 7);
    int r = 2 * P + (Ur >> 2);
    int u = Ur & 3;
    int ga = arow0 + r;
    if (ga > rowmaxA) ga = rowmaxA;
    a_src[c] = ga * KdF + u * 8;
    b_src[c] = (brow0 + r) * KdF + u * 8;
  }

#define STAGE(buf, kt)                                                                   \
  _Pragma("unroll") for (int c_ = 0; c_ < 2; ++c_) {                                     \
    gload_lds16(Ab + a_src[c_] + (kt) * 32, &lds[buf][0][(c_ * 512 + wid * 64) * 8]);    \
    gload_lds16(Bb + b_src[c_] + (kt) * 32, &lds[buf][1][(c_ * 512 + wid * 64) * 8]);    \
  }

// logical (r, lh) -> ushort offset within a 16KB half
#define AOFF(r) (((((r) >> 1)) << 6) + ((((lh) + (((r) & 1) << 2)) ^ (((r) >> 1) & 7)) << 3))

  f32x4 acc[8][4];
#pragma unroll
  for (int i = 0; i < 8; ++i)
#pragma unroll
    for (int j = 0; j < 4; ++j) acc[i][j] = (f32x4){0.f, 0.f, 0.f, 0.f};

  // prologue: 3 K-tiles in flight
  STAGE(0, 0)
  STAGE(1, 1)
  STAGE(2, 2)
  asm volatile("s_waitcnt vmcnt(8)" ::: "memory");   // buf0's 4 loads complete
  __builtin_amdgcn_s_barrier();

#pragma unroll 4
  for (int kt = 0; kt < NKT; ++kt) {
    int pf = kt + 3;
    if (pf > NKT - 1) pf = NKT - 1;   // clamped prefetch: uniform vmcnt accounting
    STAGE((kt + 3) & 3, pf)
    const ushort_t* la = &lds[kt & 3][0][0];
    const ushort_t* lb = &lds[kt & 3][1][0];
    short8 af[8], bq[4];
#pragma unroll
    for (int i = 0; i < 8; ++i)
      af[i] = *(const short8*)&la[AOFF(wm * 128 + i * 16 + lr)];
#pragma unroll
    for (int j = 0; j < 4; ++j)
      bq[j] = *(const short8*)&lb[AOFF(wn * 64 + j * 16 + lr)];
    __builtin_amdgcn_s_setprio(1);    // T5: favor MFMA-entering waves over stage-issuing
#pragma unroll
    for (int i = 0; i < 8; ++i)
#pragma unroll
      for (int j = 0; j < 4; ++j)
        acc[i][j] = __builtin_amdgcn_mfma_f32_16x16x32_bf16(af[i], bq[j], acc[i][j], 0, 0, 0);
    __builtin_amdgcn_s_setprio(0);
    asm volatile("s_waitcnt vmcnt(8)" ::: "memory");  // kt+1's loads done; kt+2/kt+3 in flight
    __builtin_amdgcn_s_barrier();
  }

  // epilogue: C[row = tm*256 + wm*128 + i*16 + lh*4 + rr][col = tn*256 + wn*64 + j*16 + lr]
  const int gcolbase = tn * 256 + wn * 64 + lr;
  float bv[4];
#pragma unroll
  for (int j = 0; j < 4; ++j) bv[j] = bias[e * Nd + gcolbase + j * 16];
#pragma unroll
  for (int i = 0; i < 8; ++i) {
#pragma unroll
    for (int rr = 0; rr < 4; ++rr) {
      int grow = tm * 256 + wm * 128 + i * 16 + lh * 4 + rr;
      if (grow < M) {
        if (MODE == 1) {
          size_t rowoff = (size_t)(ms + grow) * H_;
#pragma unroll
          for (int j = 0; j < 4; ++j) {
            float v = acc[i][j][rr] + bv[j];
            v = fmaxf(v, 0.f);
            hbo[rowoff + gcolbase + j * 16] = f2bf(v);
          }
        } else {
          int tok = perm[ms + grow];
          size_t rowoff = (size_t)tok * D_;
#pragma unroll
          for (int j = 0; j < 4; ++j)
            out[rowoff + gcolbase + j * 16] = acc[i][j][rr] + bv[j];
        }
      }
    }
  }
#undef STAGE
#undef AOFF
}

extern "C" void kernel_launch(void* const* d_in, const int* in_sizes, int n_in,
                              void* d_out, int out_size, void* d_ws, size_t ws_size,
                              hipStream_t stream) {
  const float* x  = (const float*)d_in[0];
  const float* W1 = (const float*)d_in[1];
  const float* b1 = (const float*)d_in[2];
  const float* W2 = (const float*)d_in[3];
  const float* b2 = (const float*)d_in[4];
  const float* Wr = (const float*)d_in[5];
  const float* br = (const float*)d_in[6];
  float* out = (float*)d_out;

  // workspace layout (needs ~302.3 MB)
  char* ws = (char*)d_ws;
  ushort_t* W1t   = (ushort_t*)(ws);                    // [E][H][D] bf16: 67108864 B
  ushort_t* W2t   = (ushort_t*)(ws + 67108864);         // [E][D][H] bf16: 67108864 B
  ushort_t* xg    = (ushort_t*)(ws + 134217728);        // [N][D]   bf16: 33554432 B
  ushort_t* hb    = (ushort_t*)(ws + 167772160);        // [N][H]   bf16: 134217728 B
  float*    rawbase = (float*)(ws + 301989888);         // [E][D] f32
  float*    adj   = (float*)(ws + 302022656);           // [E][D] f32
  int*      idx   = (int*)(ws + 302055424);             // [N]
  int*      perm  = (int*)(ws + 302120960);             // [N]
  int*      cursor = (int*)(ws + 302186496);            // 8
  int*      offsets = (int*)(ws + 302186624);           // 9 ints
  int*      meta   = (int*)(ws + 302186752);            // [n1, n2]
  int*      work1  = (int*)(ws + 302186880);            // <=2048 ints
  int*      work2  = (int*)(ws + 302195072);            // <=2048 ints

  init_kernel<<<32, 256, 0, stream>>>(cursor, rawbase);
  transpose_bf16<0><<<dim3(H_ / 64, D_ / 64, E_), 256, 0, stream>>>(W1, W1t, D_, H_,
                                                                    nullptr, nullptr);
  transpose_bf16<1><<<dim3(D_ / 64, H_ / 64, E_), 256, 0, stream>>>(W2, W2t, H_, D_,
                                                                    b1, rawbase);
  adj_kernel<<<32, 256, 0, stream>>>(rawbase, b2, adj);
  router_kernel<<<512, 256, 0, stream>>>(x, Wr, br, idx);
  count_scan_build<<<1, 256, 0, stream>>>(idx, offsets, work1, work2, meta);
  scatter_kernel<<<NTOK / 64, 256, 0, stream>>>(x, idx, offsets, cursor, perm, xg);
  // worst-case tile counts: sum_e ceil(cnt_e/256) <= 71 -> n1 <= 71*16=1136, n2 <= 71*4=284
  ffn_gemm<1><<<1136, 512, 0, stream>>>(xg, W1t, b1, offsets, nullptr, nullptr, hb,
                                        work1, meta + 0);
  ffn_gemm<2><<<284, 512, 0, stream>>>(hb, W2t, adj, offsets, perm, out, nullptr,
                                       work2, meta + 1);
}

// Round 13
// 600.542 us; speedup vs baseline: 5.4918x; 1.0346x over previous
//
#include <hip/hip_runtime.h>
#include <cstdint>

// Problem constants
#define E_ 8
#define D_ 1024
#define H_ 4096
#define NTOK 16384   // B*S = 4*4096

typedef unsigned short ushort_t;
typedef __attribute__((ext_vector_type(8))) short short8;
typedef __attribute__((ext_vector_type(4))) float f32x4;

__device__ __forceinline__ ushort_t f2bf(float f) {
  uint32_t u = __builtin_bit_cast(uint32_t, f);
  uint32_t r = (u + 0x7fffu + ((u >> 16) & 1u)) >> 16;  // RNE
  return (ushort_t)r;
}

__device__ __forceinline__ void gload_lds16(const void* g, void* l) {
  __builtin_amdgcn_global_load_lds(
      (const __attribute__((address_space(1))) uint32_t*)g,
      (__attribute__((address_space(3))) uint32_t*)l, 16, 0, 0);
}

// ---------------- init: zero rawbase ----------------
__global__ void init_kernel(float* rawbase) {
  int tid = threadIdx.x + blockIdx.x * 256;
  if (tid < E_ * D_) rawbase[tid] = 0.f;   // grid 32*256 = 8192 threads
}

// ---------------- transpose fp32 [E][R][C] -> bf16 [E][C][R], 64x64 tiles ----------------
// float4 (16B/lane) reads; bf16 transposed in LDS; short8 (16B) coalesced writes.
// FUSE=1 (W2 path): also accumulate rawbase[e][d] += sum_h relu(b1[e][h]) * W2[e][h][d]
template <int FUSE>
__global__ void transpose_bf16(const float* __restrict__ in, ushort_t* __restrict__ out,
                               int R, int C, const float* __restrict__ b1,
                               float* __restrict__ rawbase) {
  __shared__ ushort_t t[64][70];   // [c][r]
  __shared__ float scs[16][64];
  __shared__ float relu_b1[64];
  const int e = blockIdx.z;
  const float* ip = in + (size_t)e * R * C;
  ushort_t* op = out + (size_t)e * R * C;
  const int c0 = blockIdx.x * 64, r0 = blockIdx.y * 64;
  const int tid = threadIdx.x;
  if (FUSE) {
    if (tid < 64) relu_b1[tid] = fmaxf(b1[e * R + r0 + tid], 0.f);
    __syncthreads();
  }
  const int rsub = tid >> 4;        // 0..15
  const int c4 = (tid & 15) * 4;    // 0,4..60
  float s0 = 0.f, s1 = 0.f, s2 = 0.f, s3 = 0.f;
#pragma unroll
  for (int q = 0; q < 4; ++q) {
    int r = q * 16 + rsub;
    float4 v = *(const float4*)&ip[(size_t)(r0 + r) * C + c0 + c4];
    t[c4 + 0][r] = f2bf(v.x);
    t[c4 + 1][r] = f2bf(v.y);
    t[c4 + 2][r] = f2bf(v.z);
    t[c4 + 3][r] = f2bf(v.w);
    if (FUSE) {
      float rb = relu_b1[r];
      s0 += rb * v.x; s1 += rb * v.y; s2 += rb * v.z; s3 += rb * v.w;
    }
  }
  if (FUSE) {
    scs[rsub][c4 + 0] = s0; scs[rsub][c4 + 1] = s1;
    scs[rsub][c4 + 2] = s2; scs[rsub][c4 + 3] = s3;
  }
  __syncthreads();
  if (FUSE && tid < 64) {
    float tot = 0.f;
#pragma unroll
    for (int g = 0; g < 16; ++g) tot += scs[g][tid];
    atomicAdd(&rawbase[e * D_ + c0 + tid], tot);
  }
#pragma unroll
  for (int it = 0; it < 2; ++it) {
    int idx = it * 256 + tid;        // 0..511
    int c = idx >> 3, g = idx & 7;   // c 0..63, 8 B-groups of 8 rows
    short8 v;
#pragma unroll
    for (int k = 0; k < 8; ++k) v[k] = (short)t[c][g * 8 + k];
    *(short8*)&op[(size_t)(c0 + c) * R + r0 + g * 8] = v;
  }
}

// adj[e][d] = sum_i (rawbase[i][d] + b2[i][d]) - rawbase[e][d]
__global__ void adj_kernel(const float* __restrict__ rawbase, const float* __restrict__ b2,
                           float* __restrict__ adj) {
  int i = blockIdx.x * 256 + threadIdx.x;  // 8192
  int d = i & (D_ - 1);
  int e = i >> 10;
  float tot = 0.f;
#pragma unroll
  for (int ii = 0; ii < E_; ++ii) tot += rawbase[ii * D_ + d] + b2[ii * D_ + d];
  adj[i] = tot - rawbase[e * D_ + d];
}

// ---------------- router: fp32 logits -> argmax (first-max tiebreak). NO atomics ----------------
__global__ void router_kernel(const float* __restrict__ x, const float* __restrict__ Wr,
                              const float* __restrict__ br, int* __restrict__ idx) {
  __shared__ float wr_s[E_][D_];   // transposed Wr: wr_s[e][d]
  const int tid = threadIdx.x;
  for (int j = tid; j < E_ * D_; j += 256) {
    int e = j & 7, d = j >> 3;
    wr_s[e][d] = Wr[j];
  }
  __syncthreads();
  const int wid = tid >> 6, l = tid & 63;
  const int t0 = blockIdx.x * 32 + wid * 8;
  for (int tt = 0; tt < 8; ++tt) {
    int t = t0 + tt;
    const float4* xr4 = (const float4*)(x + (size_t)t * D_);
    float s[E_];
#pragma unroll
    for (int e = 0; e < E_; ++e) s[e] = 0.f;
#pragma unroll
    for (int q = 0; q < 4; ++q) {
      float4 xv = xr4[q * 64 + l];
#pragma unroll
      for (int e = 0; e < E_; ++e) {
        const float4 wv = *(const float4*)&wr_s[e][(q * 64 + l) * 4];
        s[e] += xv.x * wv.x + xv.y * wv.y + xv.z * wv.z + xv.w * wv.w;
      }
    }
#pragma unroll
    for (int e = 0; e < E_; ++e) {
#pragma unroll
      for (int off = 32; off > 0; off >>= 1) s[e] += __shfl_xor(s[e], off, 64);
    }
    if (l == 0) {
      float best = s[0] + br[0];
      int bi = 0;
#pragma unroll
      for (int e = 1; e < E_; ++e) {
        float v = s[e] + br[e];
        if (v > best) { best = v; bi = e; }   // strict >: first-max like argmax
      }
      idx[t] = bi;
    }
  }
}

// ---------------- fused count + scan + perm build + worklists (single block, NO atomics) ----------------
// 256x256 tiles. work1 item = (e<<16)|(tm<<8)|tn (16 tn); work2 same (4 tn). meta:[0]=n1 [1]=n2
// perm: counting sort of tokens by expert, rank = (cross-thread exclusive scan of per-thread
// histograms) -- deterministic, atomic-free.
__global__ void count_scan_build(const int* __restrict__ idx, int* __restrict__ offsets,
                                 int* __restrict__ work1, int* __restrict__ work2,
                                 int* __restrict__ meta, int* __restrict__ perm) {
  __shared__ int hist[256][E_];
  __shared__ int pb[256][E_];     // exclusive prefix (then live cursor) per thread/expert
  __shared__ int esum[E_];
  __shared__ int nt[E_], b1s[E_], b2s[E_];
  __shared__ int offs_s[E_];
  const int tid = threadIdx.x;
  int c[E_];
#pragma unroll
  for (int e = 0; e < E_; ++e) c[e] = 0;
  for (int t = tid; t < NTOK; t += 256) ++c[idx[t]];
#pragma unroll
  for (int e = 0; e < E_; ++e) hist[tid][e] = c[e];
  __syncthreads();
  {  // per-expert exclusive scan across the 256 threads: half-warp hw owns expert hw
    const int hw = tid >> 5, l32 = tid & 31;
    int carry = 0;
#pragma unroll
    for (int ch = 0; ch < 8; ++ch) {
      int v = hist[ch * 32 + l32][hw];
      int s = v;
#pragma unroll
      for (int off = 1; off < 32; off <<= 1) {
        int t = __shfl_up(s, off, 32);
        if (l32 >= off) s += t;
      }
      pb[ch * 32 + l32][hw] = carry + s - v;   // exclusive
      carry += __shfl(s, 31, 32);
    }
    if (l32 == 0) esum[hw] = carry;
  }
  __syncthreads();
  if (tid == 0) {
    int acc = 0, w1 = 0, w2 = 0;
    for (int e = 0; e < E_; ++e) {
      int s = esum[e];
      offsets[e] = acc;
      offs_s[e] = acc;
      acc += s;
      int n = (s + 255) >> 8;
      nt[e] = n;
      b1s[e] = w1; w1 += n * (H_ / 256);
      b2s[e] = w2; w2 += n * (D_ / 256);
    }
    offsets[E_] = acc;
    meta[0] = w1;
    meta[1] = w2;
  }
  __syncthreads();
  // distribute: each thread places its strided tokens at its reserved ranks
  for (int t = tid; t < NTOK; t += 256) {
    int e = idx[t];
    int p = pb[tid][e]++;
    perm[offs_s[e] + p] = t;
  }
  if (tid < E_) {
    const int e = tid, n = nt[e];
    int p = b1s[e];
    for (int tn = 0; tn < H_ / 256; ++tn)
      for (int tm = 0; tm < n; ++tm)
        work1[p++] = (e << 16) | (tm << 8) | tn;
  } else if (tid < 2 * E_) {
    const int e = tid - E_, n = nt[e];
    int p = b2s[e];
    for (int tn = 0; tn < D_ / 256; ++tn)
      for (int tm = 0; tm < n; ++tm)
        work2[p++] = (e << 16) | (tm << 8) | tn;
  }
}

// ---------------- convert: x fp32 -> xb bf16, token order, pure streaming ----------------
__global__ void convert_kernel(const float* __restrict__ x, ushort_t* __restrict__ xb) {
  const size_t i = ((size_t)blockIdx.x * 256 + threadIdx.x) * 8;
  float4 v0 = *(const float4*)(x + i);
  float4 v1 = *(const float4*)(x + i + 4);
  ushort4 o0, o1;
  o0.x = f2bf(v0.x); o0.y = f2bf(v0.y); o0.z = f2bf(v0.z); o0.w = f2bf(v0.w);
  o1.x = f2bf(v1.x); o1.y = f2bf(v1.y); o1.z = f2bf(v1.z); o1.w = f2bf(v1.w);
  *(ushort4*)(xb + i) = o0;
  *(ushort4*)(xb + i + 4) = o1;
}

// ---------------- grouped GEMM: 256x256 tile, BK=32, 4-buffer stage-ahead-3 pipeline ----------------
// (R6/R10 structure — best measured: 221 us, MfmaUtil 27.6%, 0 bank conflicts. NO setprio: R12
// measured it -7% on this structure.)
// 512 threads = 8 waves (2 M x 4 N), per-wave output 128x64. LDS: 4 bufs x {A,B} of 16 KiB.
// Two logical 64B rows pack into one 128B phys row; XOR swizzle keeps ds_read_b128 aliasing
// at 2-way (free). Per step: STAGE(kt+3 clamped) -> 12 ds_read_b128 + 32 MFMA on buf[kt&3]
// -> s_waitcnt vmcnt(8) -> s_barrier.
// MODE 1: hb[sorted] = relu(xb[perm]@W1t^T+b1) bf16 — A rows gathered via perm in the GLOBAL
// source address of global_load_lds (LDS dest stays linear).  MODE 2: out[perm] = hb@W2t^T+adj.
// NOTE (R11 lesson): acc[8][4]=128 AGPR + ~108 arch VGPR => 2 waves/SIMD max; do NOT request
// more via __launch_bounds__ or the accumulator spills to scratch (5 GB traffic).

template <int MODE>
__global__ __launch_bounds__(512, 2) void ffn_gemm(
    const ushort_t* __restrict__ A_all, const ushort_t* __restrict__ Bw,
    const float* __restrict__ bias, const int* __restrict__ offs,
    const int* __restrict__ perm, float* __restrict__ out, ushort_t* __restrict__ hbo,
    const int* __restrict__ work, const int* __restrict__ nw_p) {
  constexpr int KdF = (MODE == 1) ? D_ : H_;    // K (= row stride of A and B^T)
  constexpr int Nd = (MODE == 1) ? H_ : D_;
  constexpr int NKT = KdF / 32;                 // 32 / 128 K-steps

  const int n1 = *nw_p;
  int bid = blockIdx.x;
  if (bid >= n1) return;
  {  // m204 bijective XCD swizzle over the worklist
    int q = n1 >> 3, r = n1 & 7;
    int xcd = bid & 7, pos = bid >> 3;
    bid = (xcd < r ? xcd * (q + 1) : r * (q + 1) + (xcd - r) * q) + pos;
  }
  const int item = work[bid];
  const int e = (item >> 16) & 255, tm = (item >> 8) & 255, tn = item & 255;
  const int ms = offs[e];
  const int M = offs[e + 1] - ms;

  __shared__ __align__(16) ushort_t lds[4][2][8192];  // 4 bufs x {A,B} x 16KB = 128 KiB

  const int tid = threadIdx.x;
  const int wid = tid >> 6, l = tid & 63;
  const int wm = wid >> 2, wn = wid & 3;
  const int lr = l & 15, lh = l >> 4;

  const ushort_t* Bb = Bw + (size_t)e * ((size_t)Nd * KdF);
  const int arow0 = tm * 256;
  const int brow0 = tn * 256;
  const int rowmaxA = M - 1;

  // per-thread staging source offsets (elements). Slot s -> phys row P=s>>3, stored unit
  // U=s&7; logical unit Ur = U ^ (P&7); logical row r = 2P + (Ur>>2), col-unit u = Ur&3.
  // MODE 1: A row -> token row via perm (per-lane global addr is fine for global_load_lds).
  size_t a_src[2];
  int b_src[2];
#pragma unroll
  for (int c = 0; c < 2; ++c) {
    int s = c * 512 + tid;
    int P = s >> 3, U = s & 7;
    int Ur = U ^ (P & 7);
    int r = 2 * P + (Ur >> 2);
    int u = Ur & 3;
    int ga = arow0 + r;
    if (ga > rowmaxA) ga = rowmaxA;
    int arow = (MODE == 1) ? perm[ms + ga] : (ms + ga);
    a_src[c] = (size_t)arow * KdF + u * 8;
    b_src[c] = (brow0 + r) * KdF + u * 8;
  }

#define STAGE(buf, kt)                                                                   \
  _Pragma("unroll") for (int c_ = 0; c_ < 2; ++c_) {                                     \
    gload_lds16(A_all + a_src[c_] + (kt) * 32, &lds[buf][0][(c_ * 512 + wid * 64) * 8]); \
    gload_lds16(Bb + b_src[c_] + (kt) * 32, &lds[buf][1][(c_ * 512 + wid * 64) * 8]);    \
  }

// logical (r, lh) -> ushort offset within a 16KB half
#define AOFF(r) (((((r) >> 1)) << 6) + ((((lh) + (((r) & 1) << 2)) ^ (((r) >> 1) & 7)) << 3))

  f32x4 acc[8][4];
#pragma unroll
  for (int i = 0; i < 8; ++i)
#pragma unroll
    for (int j = 0; j < 4; ++j) acc[i][j] = (f32x4){0.f, 0.f, 0.f, 0.f};

  // prologue: 3 K-tiles in flight
  STAGE(0, 0)
  STAGE(1, 1)
  STAGE(2, 2)
  asm volatile("s_waitcnt vmcnt(8)" ::: "memory");   // buf0's 4 loads complete
  __builtin_amdgcn_s_barrier();

#pragma unroll 4
  for (int kt = 0; kt < NKT; ++kt) {
    int pf = kt + 3;
    if (pf > NKT - 1) pf = NKT - 1;   // clamped prefetch: uniform vmcnt accounting
    STAGE((kt + 3) & 3, pf)
    const ushort_t* la = &lds[kt & 3][0][0];
    const ushort_t* lb = &lds[kt & 3][1][0];
    short8 af[8], bq[4];
#pragma unroll
    for (int i = 0; i < 8; ++i)
      af[i] = *(const short8*)&la[AOFF(wm * 128 + i * 16 + lr)];
#pragma unroll
    for (int j = 0; j < 4; ++j)
      bq[j] = *(const short8*)&lb[AOFF(wn * 64 + j * 16 + lr)];
#pragma unroll
    for (int i = 0; i < 8; ++i)
#pragma unroll
      for (int j = 0; j < 4; ++j)
        acc[i][j] = __builtin_amdgcn_mfma_f32_16x16x32_bf16(af[i], bq[j], acc[i][j], 0, 0, 0);
    asm volatile("s_waitcnt vmcnt(8)" ::: "memory");  // kt+1's loads done; kt+2/kt+3 in flight
    __builtin_amdgcn_s_barrier();
  }

  // epilogue: C[row = tm*256 + wm*128 + i*16 + lh*4 + rr][col = tn*256 + wn*64 + j*16 + lr]
  const int gcolbase = tn * 256 + wn * 64 + lr;
  float bv[4];
#pragma unroll
  for (int j = 0; j < 4; ++j) bv[j] = bias[e * Nd + gcolbase + j * 16];
#pragma unroll
  for (int i = 0; i < 8; ++i) {
#pragma unroll
    for (int rr = 0; rr < 4; ++rr) {
      int grow = tm * 256 + wm * 128 + i * 16 + lh * 4 + rr;
      if (grow < M) {
        if (MODE == 1) {
          size_t rowoff = (size_t)(ms + grow) * H_;
#pragma unroll
          for (int j = 0; j < 4; ++j) {
            float v = acc[i][j][rr] + bv[j];
            v = fmaxf(v, 0.f);
            hbo[rowoff + gcolbase + j * 16] = f2bf(v);
          }
        } else {
          int tok = perm[ms + grow];
          size_t rowoff = (size_t)tok * D_;
#pragma unroll
          for (int j = 0; j < 4; ++j)
            out[rowoff + gcolbase + j * 16] = acc[i][j][rr] + bv[j];
        }
      }
    }
  }
#undef STAGE
#undef AOFF
}

extern "C" void kernel_launch(void* const* d_in, const int* in_sizes, int n_in,
                              void* d_out, int out_size, void* d_ws, size_t ws_size,
                              hipStream_t stream) {
  const float* x  = (const float*)d_in[0];
  const float* W1 = (const float*)d_in[1];
  const float* b1 = (const float*)d_in[2];
  const float* W2 = (const float*)d_in[3];
  const float* b2 = (const float*)d_in[4];
  const float* Wr = (const float*)d_in[5];
  const float* br = (const float*)d_in[6];
  float* out = (float*)d_out;

  // workspace layout (needs ~302.3 MB)
  char* ws = (char*)d_ws;
  ushort_t* W1t   = (ushort_t*)(ws);                    // [E][H][D] bf16: 67108864 B
  ushort_t* W2t   = (ushort_t*)(ws + 67108864);         // [E][D][H] bf16: 67108864 B
  ushort_t* xb    = (ushort_t*)(ws + 134217728);        // [N][D]   bf16 token-order: 33554432 B
  ushort_t* hb    = (ushort_t*)(ws + 167772160);        // [N][H]   bf16: 134217728 B
  float*    rawbase = (float*)(ws + 301989888);         // [E][D] f32
  float*    adj   = (float*)(ws + 302022656);           // [E][D] f32
  int*      idx   = (int*)(ws + 302055424);             // [N]
  int*      perm  = (int*)(ws + 302120960);             // [N]
  int*      offsets = (int*)(ws + 302186624);           // 9 ints
  int*      meta   = (int*)(ws + 302186752);            // [n1, n2]
  int*      work1  = (int*)(ws + 302186880);            // <=2048 ints
  int*      work2  = (int*)(ws + 302195072);            // <=2048 ints

  init_kernel<<<32, 256, 0, stream>>>(rawbase);
  transpose_bf16<0><<<dim3(H_ / 64, D_ / 64, E_), 256, 0, stream>>>(W1, W1t, D_, H_,
                                                                    nullptr, nullptr);
  transpose_bf16<1><<<dim3(D_ / 64, H_ / 64, E_), 256, 0, stream>>>(W2, W2t, H_, D_,
                                                                    b1, rawbase);
  adj_kernel<<<32, 256, 0, stream>>>(rawbase, b2, adj);
  router_kernel<<<512, 256, 0, stream>>>(x, Wr, br, idx);
  count_scan_build<<<1, 256, 0, stream>>>(idx, offsets, work1, work2, meta, perm);
  convert_kernel<<<NTOK * D_ / (256 * 8), 256, 0, stream>>>(x, xb);
  // worst-case tile counts: sum_e ceil(cnt_e/256) <= 71 -> n1 <= 71*16=1136, n2 <= 71*4=284
  ffn_gemm<1><<<1136, 512, 0, stream>>>(xb, W1t, b1, offsets, perm, nullptr, hb,
                                        work1, meta + 0);
  ffn_gemm<2><<<284, 512, 0, stream>>>(hb, W2t, adj, offsets, perm, out, nullptr,
                                       work2, meta + 1);
}

// Round 14
// 593.124 us; speedup vs baseline: 5.5605x; 1.0125x over previous
//
#include <hip/hip_runtime.h>
#include <cstdint>

// Problem constants
#define E_ 8
#define D_ 1024
#define H_ 4096
#define NTOK 16384   // B*S = 4*4096

typedef unsigned short ushort_t;
typedef __attribute__((ext_vector_type(8))) short short8;
typedef __attribute__((ext_vector_type(4))) float f32x4;

__device__ __forceinline__ ushort_t f2bf(float f) {
  uint32_t u = __builtin_bit_cast(uint32_t, f);
  uint32_t r = (u + 0x7fffu + ((u >> 16) & 1u)) >> 16;  // RNE
  return (ushort_t)r;
}

__device__ __forceinline__ void gload_lds16(const void* g, void* l) {
  __builtin_amdgcn_global_load_lds(
      (const __attribute__((address_space(1))) uint32_t*)g,
      (__attribute__((address_space(3))) uint32_t*)l, 16, 0, 0);
}

// ---------------- init: zero rawbase ----------------
__global__ void init_kernel(float* rawbase) {
  int tid = threadIdx.x + blockIdx.x * 256;
  if (tid < E_ * D_) rawbase[tid] = 0.f;   // grid 32*256 = 8192 threads
}

// ---------------- transpose fp32 [E][R][C] -> bf16 [E][C][R], 64x64 tiles ----------------
// float4 (16B/lane) reads; bf16 transposed in LDS; short8 (16B) coalesced writes.
// FUSE=1 (W2 path): also accumulate rawbase[e][d] += sum_h relu(b1[e][h]) * W2[e][h][d]
template <int FUSE>
__global__ void transpose_bf16(const float* __restrict__ in, ushort_t* __restrict__ out,
                               int R, int C, const float* __restrict__ b1,
                               float* __restrict__ rawbase) {
  __shared__ ushort_t t[64][70];   // [c][r]
  __shared__ float scs[16][64];
  __shared__ float relu_b1[64];
  const int e = blockIdx.z;
  const float* ip = in + (size_t)e * R * C;
  ushort_t* op = out + (size_t)e * R * C;
  const int c0 = blockIdx.x * 64, r0 = blockIdx.y * 64;
  const int tid = threadIdx.x;
  if (FUSE) {
    if (tid < 64) relu_b1[tid] = fmaxf(b1[e * R + r0 + tid], 0.f);
    __syncthreads();
  }
  const int rsub = tid >> 4;        // 0..15
  const int c4 = (tid & 15) * 4;    // 0,4..60
  float s0 = 0.f, s1 = 0.f, s2 = 0.f, s3 = 0.f;
#pragma unroll
  for (int q = 0; q < 4; ++q) {
    int r = q * 16 + rsub;
    float4 v = *(const float4*)&ip[(size_t)(r0 + r) * C + c0 + c4];
    t[c4 + 0][r] = f2bf(v.x);
    t[c4 + 1][r] = f2bf(v.y);
    t[c4 + 2][r] = f2bf(v.z);
    t[c4 + 3][r] = f2bf(v.w);
    if (FUSE) {
      float rb = relu_b1[r];
      s0 += rb * v.x; s1 += rb * v.y; s2 += rb * v.z; s3 += rb * v.w;
    }
  }
  if (FUSE) {
    scs[rsub][c4 + 0] = s0; scs[rsub][c4 + 1] = s1;
    scs[rsub][c4 + 2] = s2; scs[rsub][c4 + 3] = s3;
  }
  __syncthreads();
  if (FUSE && tid < 64) {
    float tot = 0.f;
#pragma unroll
    for (int g = 0; g < 16; ++g) tot += scs[g][tid];
    atomicAdd(&rawbase[e * D_ + c0 + tid], tot);
  }
#pragma unroll
  for (int it = 0; it < 2; ++it) {
    int idx = it * 256 + tid;        // 0..511
    int c = idx >> 3, g = idx & 7;   // c 0..63, 8 B-groups of 8 rows
    short8 v;
#pragma unroll
    for (int k = 0; k < 8; ++k) v[k] = (short)t[c][g * 8 + k];
    *(short8*)&op[(size_t)(c0 + c) * R + r0 + g * 8] = v;
  }
}

// adj[e][d] = sum_i (rawbase[i][d] + b2[i][d]) - rawbase[e][d]
__global__ void adj_kernel(const float* __restrict__ rawbase, const float* __restrict__ b2,
                           float* __restrict__ adj) {
  int i = blockIdx.x * 256 + threadIdx.x;  // 8192
  int d = i & (D_ - 1);
  int e = i >> 10;
  float tot = 0.f;
#pragma unroll
  for (int ii = 0; ii < E_; ++ii) tot += rawbase[ii * D_ + d] + b2[ii * D_ + d];
  adj[i] = tot - rawbase[e * D_ + d];
}

// ---------------- fused router + x->bf16 convert: reads x ONCE ----------------
// logits -> argmax (first-max tiebreak) -> idx[]; xb = bf16(x) written alongside.
__global__ void router_convert(const float* __restrict__ x, const float* __restrict__ Wr,
                               const float* __restrict__ br, int* __restrict__ idx,
                               ushort_t* __restrict__ xb) {
  __shared__ float wr_s[E_][D_];   // transposed Wr: wr_s[e][d]
  const int tid = threadIdx.x;
  for (int j = tid; j < E_ * D_; j += 256) {
    int e = j & 7, d = j >> 3;
    wr_s[e][d] = Wr[j];
  }
  __syncthreads();
  const int wid = tid >> 6, l = tid & 63;
  const int t0 = blockIdx.x * 32 + wid * 8;
  for (int tt = 0; tt < 8; ++tt) {
    int t = t0 + tt;
    const float4* xr4 = (const float4*)(x + (size_t)t * D_);
    ushort4* xo4 = (ushort4*)(xb + (size_t)t * D_);
    float s[E_];
#pragma unroll
    for (int e = 0; e < E_; ++e) s[e] = 0.f;
#pragma unroll
    for (int q = 0; q < 4; ++q) {
      float4 xv = xr4[q * 64 + l];
      ushort4 o;
      o.x = f2bf(xv.x); o.y = f2bf(xv.y); o.z = f2bf(xv.z); o.w = f2bf(xv.w);
      xo4[q * 64 + l] = o;
#pragma unroll
      for (int e = 0; e < E_; ++e) {
        const float4 wv = *(const float4*)&wr_s[e][(q * 64 + l) * 4];
        s[e] += xv.x * wv.x + xv.y * wv.y + xv.z * wv.z + xv.w * wv.w;
      }
    }
#pragma unroll
    for (int e = 0; e < E_; ++e) {
#pragma unroll
      for (int off = 32; off > 0; off >>= 1) s[e] += __shfl_xor(s[e], off, 64);
    }
    if (l == 0) {
      float best = s[0] + br[0];
      int bi = 0;
#pragma unroll
      for (int e = 1; e < E_; ++e) {
        float v = s[e] + br[e];
        if (v > best) { best = v; bi = e; }   // strict >: first-max like argmax
      }
      idx[t] = bi;
    }
  }
}

// ---------------- fused count + scan + perm build + worklists (single block, NO atomics) ----------------
// 256x256 tiles. work1 item = (e<<16)|(tm<<8)|tn (16 tn); work2 same (4 tn). meta:[0]=n1 [1]=n2
// perm: counting sort (cross-thread exclusive scan of per-thread histograms), deterministic.
// Worklist fill parallelized: every thread decodes linear item index -> (e,tm,tn).
__global__ void count_scan_build(const int* __restrict__ idx, int* __restrict__ offsets,
                                 int* __restrict__ work1, int* __restrict__ work2,
                                 int* __restrict__ meta, int* __restrict__ perm) {
  __shared__ int hist[256][E_];
  __shared__ int pb[256][E_];     // exclusive prefix (then live cursor) per thread/expert
  __shared__ int esum[E_];
  __shared__ int nt[E_], b1s[E_ + 1], b2s[E_ + 1];
  __shared__ int offs_s[E_];
  const int tid = threadIdx.x;
  int c[E_];
#pragma unroll
  for (int e = 0; e < E_; ++e) c[e] = 0;
  for (int t = tid; t < NTOK; t += 256) ++c[idx[t]];
#pragma unroll
  for (int e = 0; e < E_; ++e) hist[tid][e] = c[e];
  __syncthreads();
  {  // per-expert exclusive scan across the 256 threads: half-warp hw owns expert hw
    const int hw = tid >> 5, l32 = tid & 31;
    int carry = 0;
#pragma unroll
    for (int ch = 0; ch < 8; ++ch) {
      int v = hist[ch * 32 + l32][hw];
      int s = v;
#pragma unroll
      for (int off = 1; off < 32; off <<= 1) {
        int t = __shfl_up(s, off, 32);
        if (l32 >= off) s += t;
      }
      pb[ch * 32 + l32][hw] = carry + s - v;   // exclusive
      carry += __shfl(s, 31, 32);
    }
    if (l32 == 0) esum[hw] = carry;
  }
  __syncthreads();
  if (tid == 0) {
    int acc = 0, w1 = 0, w2 = 0;
    for (int e = 0; e < E_; ++e) {
      int s = esum[e];
      offsets[e] = acc;
      offs_s[e] = acc;
      acc += s;
      int n = (s + 255) >> 8;
      nt[e] = n;
      b1s[e] = w1; w1 += n * (H_ / 256);
      b2s[e] = w2; w2 += n * (D_ / 256);
    }
    offsets[E_] = acc;
    b1s[E_] = w1;
    b2s[E_] = w2;
    meta[0] = w1;
    meta[1] = w2;
  }
  __syncthreads();
  // distribute: each thread places its strided tokens at its reserved ranks
  for (int t = tid; t < NTOK; t += 256) {
    int e = idx[t];
    int p = pb[tid][e]++;
    perm[offs_s[e] + p] = t;
  }
  // parallel worklist fill: decode linear index p -> (e, tm, tn)
  const int n1 = b1s[E_], n2 = b2s[E_];
  for (int p = tid; p < n1; p += 256) {
    int e = 0;
#pragma unroll
    for (int k = 1; k < E_; ++k) e += (p >= b1s[k]);
    int loc = p - b1s[e];
    int tm = loc % nt[e], tn = loc / nt[e];
    work1[p] = (e << 16) | (tm << 8) | tn;
  }
  for (int p = tid; p < n2; p += 256) {
    int e = 0;
#pragma unroll
    for (int k = 1; k < E_; ++k) e += (p >= b2s[k]);
    int loc = p - b2s[e];
    int tm = loc % nt[e], tn = loc / nt[e];
    work2[p] = (e << 16) | (tm << 8) | tn;
  }
}

// ---------------- grouped GEMM: 256x256 tile, BK=32, 4-buffer stage-ahead-3 pipeline ----------------
// (R6/R10 structure — best measured: 221-227 us, MfmaUtil ~27.5%, 0 bank conflicts. NO setprio:
// R12 measured it -7% on this structure.)
// 512 threads = 8 waves (2 M x 4 N), per-wave output 128x64. LDS: 4 bufs x {A,B} of 16 KiB.
// Two logical 64B rows pack into one 128B phys row; XOR swizzle keeps ds_read_b128 aliasing
// at 2-way (free). Per step: STAGE(kt+3 clamped) -> 12 ds_read_b128 + 32 MFMA on buf[kt&3]
// -> s_waitcnt vmcnt(8) -> s_barrier.
// MODE 1: hb[sorted] = relu(xb[perm]@W1t^T+b1) bf16 — A rows gathered via perm in the GLOBAL
// source address of global_load_lds (LDS dest stays linear).  MODE 2: out[perm] = hb@W2t^T+adj.
// NOTE (R11 lesson): acc[8][4]=128 AGPR + ~108 arch VGPR => 2 waves/SIMD max; do NOT request
// more via __launch_bounds__ or the accumulator spills to scratch (5 GB traffic).

template <int MODE>
__global__ __launch_bounds__(512, 2) void ffn_gemm(
    const ushort_t* __restrict__ A_all, const ushort_t* __restrict__ Bw,
    const float* __restrict__ bias, const int* __restrict__ offs,
    const int* __restrict__ perm, float* __restrict__ out, ushort_t* __restrict__ hbo,
    const int* __restrict__ work, const int* __restrict__ nw_p) {
  constexpr int KdF = (MODE == 1) ? D_ : H_;    // K (= row stride of A and B^T)
  constexpr int Nd = (MODE == 1) ? H_ : D_;
  constexpr int NKT = KdF / 32;                 // 32 / 128 K-steps

  const int n1 = *nw_p;
  int bid = blockIdx.x;
  if (bid >= n1) return;
  {  // m204 bijective XCD swizzle over the worklist
    int q = n1 >> 3, r = n1 & 7;
    int xcd = bid & 7, pos = bid >> 3;
    bid = (xcd < r ? xcd * (q + 1) : r * (q + 1) + (xcd - r) * q) + pos;
  }
  const int item = work[bid];
  const int e = (item >> 16) & 255, tm = (item >> 8) & 255, tn = item & 255;
  const int ms = offs[e];
  const int M = offs[e + 1] - ms;

  __shared__ __align__(16) ushort_t lds[4][2][8192];  // 4 bufs x {A,B} x 16KB = 128 KiB

  const int tid = threadIdx.x;
  const int wid = tid >> 6, l = tid & 63;
  const int wm = wid >> 2, wn = wid & 3;
  const int lr = l & 15, lh = l >> 4;

  const ushort_t* Bb = Bw + (size_t)e * ((size_t)Nd * KdF);
  const int arow0 = tm * 256;
  const int brow0 = tn * 256;
  const int rowmaxA = M - 1;

  // per-thread staging source offsets (elements). Slot s -> phys row P=s>>3, stored unit
  // U=s&7; logical unit Ur = U ^ (P&7); logical row r = 2P + (Ur>>2), col-unit u = Ur&3.
  // MODE 1: A row -> token row via perm (per-lane global addr is fine for global_load_lds).
  size_t a_src[2];
  int b_src[2];
#pragma unroll
  for (int c = 0; c < 2; ++c) {
    int s = c * 512 + tid;
    int P = s >> 3, U = s & 7;
    int Ur = U ^ (P & 7);
    int r = 2 * P + (Ur >> 2);
    int u = Ur & 3;
    int ga = arow0 + r;
    if (ga > rowmaxA) ga = rowmaxA;
    int arow = (MODE == 1) ? perm[ms + ga] : (ms + ga);
    a_src[c] = (size_t)arow * KdF + u * 8;
    b_src[c] = (brow0 + r) * KdF + u * 8;
  }

#define STAGE(buf, kt)                                                                   \
  _Pragma("unroll") for (int c_ = 0; c_ < 2; ++c_) {                                     \
    gload_lds16(A_all + a_src[c_] + (kt) * 32, &lds[buf][0][(c_ * 512 + wid * 64) * 8]); \
    gload_lds16(Bb + b_src[c_] + (kt) * 32, &lds[buf][1][(c_ * 512 + wid * 64) * 8]);    \
  }

// logical (r, lh) -> ushort offset within a 16KB half
#define AOFF(r) (((((r) >> 1)) << 6) + ((((lh) + (((r) & 1) << 2)) ^ (((r) >> 1) & 7)) << 3))

  f32x4 acc[8][4];
#pragma unroll
  for (int i = 0; i < 8; ++i)
#pragma unroll
    for (int j = 0; j < 4; ++j) acc[i][j] = (f32x4){0.f, 0.f, 0.f, 0.f};

  // prologue: 3 K-tiles in flight
  STAGE(0, 0)
  STAGE(1, 1)
  STAGE(2, 2)
  asm volatile("s_waitcnt vmcnt(8)" ::: "memory");   // buf0's 4 loads complete
  __builtin_amdgcn_s_barrier();

#pragma unroll 4
  for (int kt = 0; kt < NKT; ++kt) {
    int pf = kt + 3;
    if (pf > NKT - 1) pf = NKT - 1;   // clamped prefetch: uniform vmcnt accounting
    STAGE((kt + 3) & 3, pf)
    const ushort_t* la = &lds[kt & 3][0][0];
    const ushort_t* lb = &lds[kt & 3][1][0];
    short8 af[8], bq[4];
#pragma unroll
    for (int i = 0; i < 8; ++i)
      af[i] = *(const short8*)&la[AOFF(wm * 128 + i * 16 + lr)];
#pragma unroll
    for (int j = 0; j < 4; ++j)
      bq[j] = *(const short8*)&lb[AOFF(wn * 64 + j * 16 + lr)];
#pragma unroll
    for (int i = 0; i < 8; ++i)
#pragma unroll
      for (int j = 0; j < 4; ++j)
        acc[i][j] = __builtin_amdgcn_mfma_f32_16x16x32_bf16(af[i], bq[j], acc[i][j], 0, 0, 0);
    asm volatile("s_waitcnt vmcnt(8)" ::: "memory");  // kt+1's loads done; kt+2/kt+3 in flight
    __builtin_amdgcn_s_barrier();
  }

  // epilogue: C[row = tm*256 + wm*128 + i*16 + lh*4 + rr][col = tn*256 + wn*64 + j*16 + lr]
  const int gcolbase = tn * 256 + wn * 64 + lr;
  float bv[4];
#pragma unroll
  for (int j = 0; j < 4; ++j) bv[j] = bias[e * Nd + gcolbase + j * 16];
#pragma unroll
  for (int i = 0; i < 8; ++i) {
#pragma unroll
    for (int rr = 0; rr < 4; ++rr) {
      int grow = tm * 256 + wm * 128 + i * 16 + lh * 4 + rr;
      if (grow < M) {
        if (MODE == 1) {
          size_t rowoff = (size_t)(ms + grow) * H_;
#pragma unroll
          for (int j = 0; j < 4; ++j) {
            float v = acc[i][j][rr] + bv[j];
            v = fmaxf(v, 0.f);
            hbo[rowoff + gcolbase + j * 16] = f2bf(v);
          }
        } else {
          int tok = perm[ms + grow];
          size_t rowoff = (size_t)tok * D_;
#pragma unroll
          for (int j = 0; j < 4; ++j)
            out[rowoff + gcolbase + j * 16] = acc[i][j][rr] + bv[j];
        }
      }
    }
  }
#undef STAGE
#undef AOFF
}

extern "C" void kernel_launch(void* const* d_in, const int* in_sizes, int n_in,
                              void* d_out, int out_size, void* d_ws, size_t ws_size,
                              hipStream_t stream) {
  const float* x  = (const float*)d_in[0];
  const float* W1 = (const float*)d_in[1];
  const float* b1 = (const float*)d_in[2];
  const float* W2 = (const float*)d_in[3];
  const float* b2 = (const float*)d_in[4];
  const float* Wr = (const float*)d_in[5];
  const float* br = (const float*)d_in[6];
  float* out = (float*)d_out;

  // workspace layout (needs ~302.3 MB)
  char* ws = (char*)d_ws;
  ushort_t* W1t   = (ushort_t*)(ws);                    // [E][H][D] bf16: 67108864 B
  ushort_t* W2t   = (ushort_t*)(ws + 67108864);         // [E][D][H] bf16: 67108864 B
  ushort_t* xb    = (ushort_t*)(ws + 134217728);        // [N][D]   bf16 token-order: 33554432 B
  ushort_t* hb    = (ushort_t*)(ws + 167772160);        // [N][H]   bf16: 134217728 B
  float*    rawbase = (float*)(ws + 301989888);         // [E][D] f32
  float*    adj   = (float*)(ws + 302022656);           // [E][D] f32
  int*      idx   = (int*)(ws + 302055424);             // [N]
  int*      perm  = (int*)(ws + 302120960);             // [N]
  int*      offsets = (int*)(ws + 302186624);           // 9 ints
  int*      meta   = (int*)(ws + 302186752);            // [n1, n2]
  int*      work1  = (int*)(ws + 302186880);            // <=2048 ints
  int*      work2  = (int*)(ws + 302195072);            // <=2048 ints

  init_kernel<<<32, 256, 0, stream>>>(rawbase);
  transpose_bf16<0><<<dim3(H_ / 64, D_ / 64, E_), 256, 0, stream>>>(W1, W1t, D_, H_,
                                                                    nullptr, nullptr);
  transpose_bf16<1><<<dim3(D_ / 64, H_ / 64, E_), 256, 0, stream>>>(W2, W2t, H_, D_,
                                                                    b1, rawbase);
  adj_kernel<<<32, 256, 0, stream>>>(rawbase, b2, adj);
  router_convert<<<512, 256, 0, stream>>>(x, Wr, br, idx, xb);
  count_scan_build<<<1, 256, 0, stream>>>(idx, offsets, work1, work2, meta, perm);
  // worst-case tile counts: sum_e ceil(cnt_e/256) <= 71 -> n1 <= 71*16=1136, n2 <= 71*4=284
  ffn_gemm<1><<<1136, 512, 0, stream>>>(xb, W1t, b1, offsets, perm, nullptr, hb,
                                        work1, meta + 0);
  ffn_gemm<2><<<284, 512, 0, stream>>>(hb, W2t, adj, offsets, perm, out, nullptr,
                                       work2, meta + 1);
}

// Round 15
// 588.492 us; speedup vs baseline: 5.6043x; 1.0079x over previous
//
#include <hip/hip_runtime.h>
#include <cstdint>

// Problem constants
#define E_ 8
#define D_ 1024
#define H_ 4096
#define NTOK 16384   // B*S = 4*4096

typedef unsigned short ushort_t;
typedef __attribute__((ext_vector_type(8))) short short8;
typedef __attribute__((ext_vector_type(4))) float f32x4;

__device__ __forceinline__ ushort_t f2bf(float f) {
  uint32_t u = __builtin_bit_cast(uint32_t, f);
  uint32_t r = (u + 0x7fffu + ((u >> 16) & 1u)) >> 16;  // RNE
  return (ushort_t)r;
}

__device__ __forceinline__ void gload_lds16(const void* g, void* l) {
  __builtin_amdgcn_global_load_lds(
      (const __attribute__((address_space(1))) uint32_t*)g,
      (__attribute__((address_space(3))) uint32_t*)l, 16, 0, 0);
}

// ---------------- init: zero rawbase ----------------
__global__ void init_kernel(float* rawbase) {
  int tid = threadIdx.x + blockIdx.x * 256;
  if (tid < E_ * D_) rawbase[tid] = 0.f;   // grid 32*256 = 8192 threads
}

// ---------------- transpose fp32 [E][R][C] -> bf16 [E][C][R], 64x64 tiles ----------------
// float4 (16B/lane) reads; bf16 transposed in LDS; short8 (16B) coalesced writes.
// FUSE=1 (W2 path): also accumulate rawbase[e][d] += sum_h relu(b1[e][h]) * W2[e][h][d]
template <int FUSE>
__global__ void transpose_bf16(const float* __restrict__ in, ushort_t* __restrict__ out,
                               int R, int C, const float* __restrict__ b1,
                               float* __restrict__ rawbase) {
  __shared__ ushort_t t[64][70];   // [c][r]
  __shared__ float scs[16][64];
  __shared__ float relu_b1[64];
  const int e = blockIdx.z;
  const float* ip = in + (size_t)e * R * C;
  ushort_t* op = out + (size_t)e * R * C;
  const int c0 = blockIdx.x * 64, r0 = blockIdx.y * 64;
  const int tid = threadIdx.x;
  if (FUSE) {
    if (tid < 64) relu_b1[tid] = fmaxf(b1[e * R + r0 + tid], 0.f);
    __syncthreads();
  }
  const int rsub = tid >> 4;        // 0..15
  const int c4 = (tid & 15) * 4;    // 0,4..60
  float s0 = 0.f, s1 = 0.f, s2 = 0.f, s3 = 0.f;
#pragma unroll
  for (int q = 0; q < 4; ++q) {
    int r = q * 16 + rsub;
    float4 v = *(const float4*)&ip[(size_t)(r0 + r) * C + c0 + c4];
    t[c4 + 0][r] = f2bf(v.x);
    t[c4 + 1][r] = f2bf(v.y);
    t[c4 + 2][r] = f2bf(v.z);
    t[c4 + 3][r] = f2bf(v.w);
    if (FUSE) {
      float rb = relu_b1[r];
      s0 += rb * v.x; s1 += rb * v.y; s2 += rb * v.z; s3 += rb * v.w;
    }
  }
  if (FUSE) {
    scs[rsub][c4 + 0] = s0; scs[rsub][c4 + 1] = s1;
    scs[rsub][c4 + 2] = s2; scs[rsub][c4 + 3] = s3;
  }
  __syncthreads();
  if (FUSE && tid < 64) {
    float tot = 0.f;
#pragma unroll
    for (int g = 0; g < 16; ++g) tot += scs[g][tid];
    atomicAdd(&rawbase[e * D_ + c0 + tid], tot);
  }
#pragma unroll
  for (int it = 0; it < 2; ++it) {
    int idx = it * 256 + tid;        // 0..511
    int c = idx >> 3, g = idx & 7;   // c 0..63, 8 B-groups of 8 rows
    short8 v;
#pragma unroll
    for (int k = 0; k < 8; ++k) v[k] = (short)t[c][g * 8 + k];
    *(short8*)&op[(size_t)(c0 + c) * R + r0 + g * 8] = v;
  }
}

// adj[e][d] = sum_i (rawbase[i][d] + b2[i][d]) - rawbase[e][d]
__global__ void adj_kernel(const float* __restrict__ rawbase, const float* __restrict__ b2,
                           float* __restrict__ adj) {
  int i = blockIdx.x * 256 + threadIdx.x;  // 8192
  int d = i & (D_ - 1);
  int e = i >> 10;
  float tot = 0.f;
#pragma unroll
  for (int ii = 0; ii < E_; ++ii) tot += rawbase[ii * D_ + d] + b2[ii * D_ + d];
  adj[i] = tot - rawbase[e * D_ + d];
}

// ---------------- fused router + x->bf16 convert: reads x ONCE ----------------
// logits -> argmax (first-max tiebreak) -> idx[]; xb = bf16(x) written alongside.
__global__ void router_convert(const float* __restrict__ x, const float* __restrict__ Wr,
                               const float* __restrict__ br, int* __restrict__ idx,
                               ushort_t* __restrict__ xb) {
  __shared__ float wr_s[E_][D_];   // transposed Wr: wr_s[e][d]
  const int tid = threadIdx.x;
  for (int j = tid; j < E_ * D_; j += 256) {
    int e = j & 7, d = j >> 3;
    wr_s[e][d] = Wr[j];
  }
  __syncthreads();
  const int wid = tid >> 6, l = tid & 63;
  const int t0 = blockIdx.x * 32 + wid * 8;
  for (int tt = 0; tt < 8; ++tt) {
    int t = t0 + tt;
    const float4* xr4 = (const float4*)(x + (size_t)t * D_);
    ushort4* xo4 = (ushort4*)(xb + (size_t)t * D_);
    float s[E_];
#pragma unroll
    for (int e = 0; e < E_; ++e) s[e] = 0.f;
#pragma unroll
    for (int q = 0; q < 4; ++q) {
      float4 xv = xr4[q * 64 + l];
      ushort4 o;
      o.x = f2bf(xv.x); o.y = f2bf(xv.y); o.z = f2bf(xv.z); o.w = f2bf(xv.w);
      xo4[q * 64 + l] = o;
#pragma unroll
      for (int e = 0; e < E_; ++e) {
        const float4 wv = *(const float4*)&wr_s[e][(q * 64 + l) * 4];
        s[e] += xv.x * wv.x + xv.y * wv.y + xv.z * wv.z + xv.w * wv.w;
      }
    }
#pragma unroll
    for (int e = 0; e < E_; ++e) {
#pragma unroll
      for (int off = 32; off > 0; off >>= 1) s[e] += __shfl_xor(s[e], off, 64);
    }
    if (l == 0) {
      float best = s[0] + br[0];
      int bi = 0;
#pragma unroll
      for (int e = 1; e < E_; ++e) {
        float v = s[e] + br[e];
        if (v > best) { best = v; bi = e; }   // strict >: first-max like argmax
      }
      idx[t] = bi;
    }
  }
}

// ---------------- fused count + scan + perm build + worklists (single block, NO atomics) ----------------
// 256x256 tiles. work item = (e<<16)|(tm<<8)|tn. meta:[0]=n1 [1]=n2
// perm: counting sort (cross-thread exclusive scan of per-thread histograms), deterministic.
// Worklist SUPER-TILED for L2 locality: per expert, order = [tm-group of 4][tn][tm in group].
// With the GEMM's contiguous-chunk-per-XCD swizzle, each XCD then holds 4 A-panels (2 MB,
// L2-resident) across all tn instead of re-fetching every A panel per tn (~3x less L2-miss).
__global__ void count_scan_build(const int* __restrict__ idx, int* __restrict__ offsets,
                                 int* __restrict__ work1, int* __restrict__ work2,
                                 int* __restrict__ meta, int* __restrict__ perm) {
  __shared__ int hist[256][E_];
  __shared__ int pb[256][E_];     // exclusive prefix (then live cursor) per thread/expert
  __shared__ int esum[E_];
  __shared__ int nt[E_], b1s[E_ + 1], b2s[E_ + 1];
  __shared__ int offs_s[E_];
  const int tid = threadIdx.x;
  int c[E_];
#pragma unroll
  for (int e = 0; e < E_; ++e) c[e] = 0;
  for (int t = tid; t < NTOK; t += 256) ++c[idx[t]];
#pragma unroll
  for (int e = 0; e < E_; ++e) hist[tid][e] = c[e];
  __syncthreads();
  {  // per-expert exclusive scan across the 256 threads: half-warp hw owns expert hw
    const int hw = tid >> 5, l32 = tid & 31;
    int carry = 0;
#pragma unroll
    for (int ch = 0; ch < 8; ++ch) {
      int v = hist[ch * 32 + l32][hw];
      int s = v;
#pragma unroll
      for (int off = 1; off < 32; off <<= 1) {
        int t = __shfl_up(s, off, 32);
        if (l32 >= off) s += t;
      }
      pb[ch * 32 + l32][hw] = carry + s - v;   // exclusive
      carry += __shfl(s, 31, 32);
    }
    if (l32 == 0) esum[hw] = carry;
  }
  __syncthreads();
  if (tid == 0) {
    int acc = 0, w1 = 0, w2 = 0;
    for (int e = 0; e < E_; ++e) {
      int s = esum[e];
      offsets[e] = acc;
      offs_s[e] = acc;
      acc += s;
      int n = (s + 255) >> 8;
      nt[e] = n;
      b1s[e] = w1; w1 += n * (H_ / 256);
      b2s[e] = w2; w2 += n * (D_ / 256);
    }
    offsets[E_] = acc;
    b1s[E_] = w1;
    b2s[E_] = w2;
    meta[0] = w1;
    meta[1] = w2;
  }
  __syncthreads();
  // distribute: each thread places its strided tokens at its reserved ranks
  for (int t = tid; t < NTOK; t += 256) {
    int e = idx[t];
    int p = pb[tid][e]++;
    perm[offs_s[e] + p] = t;
  }
  // super-tiled worklist fill: 8 threads for work1, 8 for work2 (<=144 items each)
  if (tid < E_) {
    const int e = tid, n = nt[e];
    int p = b1s[e];
    for (int tmg = 0; tmg < n; tmg += 4) {
      int tmh = (tmg + 4 < n) ? (tmg + 4) : n;
      for (int tn = 0; tn < H_ / 256; ++tn)
        for (int tm = tmg; tm < tmh; ++tm)
          work1[p++] = (e << 16) | (tm << 8) | tn;
    }
  } else if (tid < 2 * E_) {
    const int e = tid - E_, n = nt[e];
    int p = b2s[e];
    for (int tmg = 0; tmg < n; tmg += 4) {
      int tmh = (tmg + 4 < n) ? (tmg + 4) : n;
      for (int tn = 0; tn < D_ / 256; ++tn)
        for (int tm = tmg; tm < tmh; ++tm)
          work2[p++] = (e << 16) | (tm << 8) | tn;
    }
  }
}

// ---------------- grouped GEMM: 256x256 tile, BK=32, 4-buffer stage-ahead-3 pipeline ----------------
// (R6/R10 structure — best measured: 221-227 us, MfmaUtil ~27.5%, 0 bank conflicts. NO setprio:
// R12 measured it -7% on this structure.)
// 512 threads = 8 waves (2 M x 4 N), per-wave output 128x64. LDS: 4 bufs x {A,B} of 16 KiB.
// Two logical 64B rows pack into one 128B phys row; XOR swizzle keeps ds_read_b128 aliasing
// at 2-way (free). Per step: STAGE(kt+3 clamped) -> 12 ds_read_b128 + 32 MFMA on buf[kt&3]
// -> s_waitcnt vmcnt(8) -> s_barrier.
// MODE 1: hb[sorted] = relu(xb[perm]@W1t^T+b1) bf16 — A rows gathered via perm in the GLOBAL
// source address of global_load_lds (LDS dest stays linear).  MODE 2: out[perm] = hb@W2t^T+adj.
// NOTE (R11 lesson): acc[8][4]=128 AGPR + ~108 arch VGPR => 2 waves/SIMD max; do NOT request
// more via __launch_bounds__ or the accumulator spills to scratch (5 GB traffic).

template <int MODE>
__global__ __launch_bounds__(512, 2) void ffn_gemm(
    const ushort_t* __restrict__ A_all, const ushort_t* __restrict__ Bw,
    const float* __restrict__ bias, const int* __restrict__ offs,
    const int* __restrict__ perm, float* __restrict__ out, ushort_t* __restrict__ hbo,
    const int* __restrict__ work, const int* __restrict__ nw_p) {
  constexpr int KdF = (MODE == 1) ? D_ : H_;    // K (= row stride of A and B^T)
  constexpr int Nd = (MODE == 1) ? H_ : D_;
  constexpr int NKT = KdF / 32;                 // 32 / 128 K-steps

  const int n1 = *nw_p;
  int bid = blockIdx.x;
  if (bid >= n1) return;
  {  // m204 bijective XCD swizzle over the worklist (contiguous chunk per XCD)
    int q = n1 >> 3, r = n1 & 7;
    int xcd = bid & 7, pos = bid >> 3;
    bid = (xcd < r ? xcd * (q + 1) : r * (q + 1) + (xcd - r) * q) + pos;
  }
  const int item = work[bid];
  const int e = (item >> 16) & 255, tm = (item >> 8) & 255, tn = item & 255;
  const int ms = offs[e];
  const int M = offs[e + 1] - ms;

  __shared__ __align__(16) ushort_t lds[4][2][8192];  // 4 bufs x {A,B} x 16KB = 128 KiB

  const int tid = threadIdx.x;
  const int wid = tid >> 6, l = tid & 63;
  const int wm = wid >> 2, wn = wid & 3;
  const int lr = l & 15, lh = l >> 4;

  const ushort_t* Bb = Bw + (size_t)e * ((size_t)Nd * KdF);
  const int arow0 = tm * 256;
  const int brow0 = tn * 256;
  const int rowmaxA = M - 1;

  // per-thread staging source offsets (elements). Slot s -> phys row P=s>>3, stored unit
  // U=s&7; logical unit Ur = U ^ (P&7); logical row r = 2P + (Ur>>2), col-unit u = Ur&3.
  // MODE 1: A row -> token row via perm (per-lane global addr is fine for global_load_lds).
  size_t a_src[2];
  int b_src[2];
#pragma unroll
  for (int c = 0; c < 2; ++c) {
    int s = c * 512 + tid;
    int P = s >> 3, U = s & 7;
    int Ur = U ^ (P & 7);
    int r = 2 * P + (Ur >> 2);
    int u = Ur & 3;
    int ga = arow0 + r;
    if (ga > rowmaxA) ga = rowmaxA;
    int arow = (MODE == 1) ? perm[ms + ga] : (ms + ga);
    a_src[c] = (size_t)arow * KdF + u * 8;
    b_src[c] = (brow0 + r) * KdF + u * 8;
  }

#define STAGE(buf, kt)                                                                   \
  _Pragma("unroll") for (int c_ = 0; c_ < 2; ++c_) {                                     \
    gload_lds16(A_all + a_src[c_] + (kt) * 32, &lds[buf][0][(c_ * 512 + wid * 64) * 8]); \
    gload_lds16(Bb + b_src[c_] + (kt) * 32, &lds[buf][1][(c_ * 512 + wid * 64) * 8]);    \
  }

// logical (r, lh) -> ushort offset within a 16KB half
#define AOFF(r) (((((r) >> 1)) << 6) + ((((lh) + (((r) & 1) << 2)) ^ (((r) >> 1) & 7)) << 3))

  f32x4 acc[8][4];
#pragma unroll
  for (int i = 0; i < 8; ++i)
#pragma unroll
    for (int j = 0; j < 4; ++j) acc[i][j] = (f32x4){0.f, 0.f, 0.f, 0.f};

  // prologue: 3 K-tiles in flight
  STAGE(0, 0)
  STAGE(1, 1)
  STAGE(2, 2)
  asm volatile("s_waitcnt vmcnt(8)" ::: "memory");   // buf0's 4 loads complete
  __builtin_amdgcn_s_barrier();

#pragma unroll 4
  for (int kt = 0; kt < NKT; ++kt) {
    int pf = kt + 3;
    if (pf > NKT - 1) pf = NKT - 1;   // clamped prefetch: uniform vmcnt accounting
    STAGE((kt + 3) & 3, pf)
    const ushort_t* la = &lds[kt & 3][0][0];
    const ushort_t* lb = &lds[kt & 3][1][0];
    short8 af[8], bq[4];
#pragma unroll
    for (int i = 0; i < 8; ++i)
      af[i] = *(const short8*)&la[AOFF(wm * 128 + i * 16 + lr)];
#pragma unroll
    for (int j = 0; j < 4; ++j)
      bq[j] = *(const short8*)&lb[AOFF(wn * 64 + j * 16 + lr)];
#pragma unroll
    for (int i = 0; i < 8; ++i)
#pragma unroll
      for (int j = 0; j < 4; ++j)
        acc[i][j] = __builtin_amdgcn_mfma_f32_16x16x32_bf16(af[i], bq[j], acc[i][j], 0, 0, 0);
    asm volatile("s_waitcnt vmcnt(8)" ::: "memory");  // kt+1's loads done; kt+2/kt+3 in flight
    __builtin_amdgcn_s_barrier();
  }

  // epilogue: C[row = tm*256 + wm*128 + i*16 + lh*4 + rr][col = tn*256 + wn*64 + j*16 + lr]
  const int gcolbase = tn * 256 + wn * 64 + lr;
  float bv[4];
#pragma unroll
  for (int j = 0; j < 4; ++j) bv[j] = bias[e * Nd + gcolbase + j * 16];
#pragma unroll
  for (int i = 0; i < 8; ++i) {
#pragma unroll
    for (int rr = 0; rr < 4; ++rr) {
      int grow = tm * 256 + wm * 128 + i * 16 + lh * 4 + rr;
      if (grow < M) {
        if (MODE == 1) {
          size_t rowoff = (size_t)(ms + grow) * H_;
#pragma unroll
          for (int j = 0; j < 4; ++j) {
            float v = acc[i][j][rr] + bv[j];
            v = fmaxf(v, 0.f);
            hbo[rowoff + gcolbase + j * 16] = f2bf(v);
          }
        } else {
          int tok = perm[ms + grow];
          size_t rowoff = (size_t)tok * D_;
#pragma unroll
          for (int j = 0; j < 4; ++j)
            out[rowoff + gcolbase + j * 16] = acc[i][j][rr] + bv[j];
        }
      }
    }
  }
#undef STAGE
#undef AOFF
}

extern "C" void kernel_launch(void* const* d_in, const int* in_sizes, int n_in,
                              void* d_out, int out_size, void* d_ws, size_t ws_size,
                              hipStream_t stream) {
  const float* x  = (const float*)d_in[0];
  const float* W1 = (const float*)d_in[1];
  const float* b1 = (const float*)d_in[2];
  const float* W2 = (const float*)d_in[3];
  const float* b2 = (const float*)d_in[4];
  const float* Wr = (const float*)d_in[5];
  const float* br = (const float*)d_in[6];
  float* out = (float*)d_out;

  // workspace layout (needs ~302.3 MB)
  char* ws = (char*)d_ws;
  ushort_t* W1t   = (ushort_t*)(ws);                    // [E][H][D] bf16: 67108864 B
  ushort_t* W2t   = (ushort_t*)(ws + 67108864);         // [E][D][H] bf16: 67108864 B
  ushort_t* xb    = (ushort_t*)(ws + 134217728);        // [N][D]   bf16 token-order: 33554432 B
  ushort_t* hb    = (ushort_t*)(ws + 167772160);        // [N][H]   bf16: 134217728 B
  float*    rawbase = (float*)(ws + 301989888);         // [E][D] f32
  float*    adj   = (float*)(ws + 302022656);           // [E][D] f32
  int*      idx   = (int*)(ws + 302055424);             // [N]
  int*      perm  = (int*)(ws + 302120960);             // [N]
  int*      offsets = (int*)(ws + 302186624);           // 9 ints
  int*      meta   = (int*)(ws + 302186752);            // [n1, n2]
  int*      work1  = (int*)(ws + 302186880);            // <=2048 ints
  int*      work2  = (int*)(ws + 302195072);            // <=2048 ints

  init_kernel<<<32, 256, 0, stream>>>(rawbase);
  transpose_bf16<0><<<dim3(H_ / 64, D_ / 64, E_), 256, 0, stream>>>(W1, W1t, D_, H_,
                                                                    nullptr, nullptr);
  transpose_bf16<1><<<dim3(D_ / 64, H_ / 64, E_), 256, 0, stream>>>(W2, W2t, H_, D_,
                                                                    b1, rawbase);
  adj_kernel<<<32, 256, 0, stream>>>(rawbase, b2, adj);
  router_convert<<<512, 256, 0, stream>>>(x, Wr, br, idx, xb);
  count_scan_build<<<1, 256, 0, stream>>>(idx, offsets, work1, work2, meta, perm);
  // worst-case tile counts: sum_e ceil(cnt_e/256) <= 71 -> n1 <= 71*16=1136, n2 <= 71*4=284
  ffn_gemm<1><<<1136, 512, 0, stream>>>(xb, W1t, b1, offsets, perm, nullptr, hb,
                                        work1, meta + 0);
  ffn_gemm<2><<<284, 512, 0, stream>>>(hb, W2t, adj, offsets, perm, out, nullptr,
                                       work2, meta + 1);
}